// Round 14
// baseline (4064.292 us; speedup 1.0000x reference)
//
#include <hip/hip_runtime.h>

typedef unsigned short u16;
typedef unsigned int u32;
typedef unsigned long long u64;
typedef short bf16x8 __attribute__((ext_vector_type(8)));
typedef float f32x4 __attribute__((ext_vector_type(4)));
typedef unsigned u32x4 __attribute__((ext_vector_type(4)));

#define NB 128
#define NT 512
#define NV 1024
#define NE 256
#define NH 512
#define NG 2048

#define POISON64 0xFFFFFFFFFFFFFFFFULL
#define POISON32 0xFFFFFFFFu
#define HEX_T 65536  // elements per t-slot: 8 groups x 16 slots x 16 b x 32 j
#define PROBE_CYCLES 480000ULL  // ~0.2 ms @ 2.4 GHz

__device__ __forceinline__ u16 f2bf(float f) {
  union { float f; unsigned u; } v; v.f = f;
  unsigned r = v.u + 0x7FFFu + ((v.u >> 16) & 1u);
  return (u16)(r >> 16);
}
__device__ __forceinline__ float bf2f(u16 u) {
  union { unsigned u; float f; } v; v.u = ((unsigned)u) << 16;
  return v.f;
}
__device__ __forceinline__ float sigm(float x) { return 1.f / (1.f + __expf(-x)); }
__device__ __forceinline__ float tanh_f(float x) {
  x = fminf(fmaxf(x, -20.f), 20.f);
  float e = __expf(2.f * x);
  return (e - 1.f) / (e + 1.f);
}
__device__ __forceinline__ u64 memtime() {
  u64 t;
  asm volatile("s_memtime %0\n\ts_waitcnt lgkmcnt(0)" : "=s"(t));
  return t;
}

#define MFMA16(a, b, c) __builtin_amdgcn_mfma_f32_16x16x32_bf16((a), (b), (c), 0, 0, 0)

// plain cached prefetch load (gates stream)
__device__ __forceinline__ uint2 pf_load_u64(const void* p) {
  uint2 r;
  asm volatile("global_load_dwordx2 %0, %1, off" : "=v"(r) : "v"(p) : "memory");
  return r;
}
// exchange store: ATOMIC exchange (R13-proven identical to sc0sc1 store;
// executes at the coherence point, result discarded).
__device__ __forceinline__ void ex_store(u16* p, u64 v) {
  (void)__hip_atomic_exchange((u64*)p, v, __ATOMIC_RELAXED, __HIP_MEMORY_SCOPE_AGENT);
}
// exchange/poll load of 32B. fast: sc0 only -> L2-served. slow: sc0 sc1 -> L3.
__device__ __forceinline__ void ex_load2(const u16* p, bool fast, u32x4& q0, u32x4& q1) {
  if (fast) {
    asm volatile(
        "global_load_dwordx4 %0, %2, off sc0\n\t"
        "global_load_dwordx4 %1, %3, off sc0\n\t"
        "s_waitcnt vmcnt(0)"
        : "=&v"(q0), "=&v"(q1)
        : "v"(p), "v"(p + 8)
        : "memory");
  } else {
    asm volatile(
        "global_load_dwordx4 %0, %2, off sc0 sc1\n\t"
        "global_load_dwordx4 %1, %3, off sc0 sc1\n\t"
        "s_waitcnt vmcnt(0)"
        : "=&v"(q0), "=&v"(q1)
        : "v"(p), "v"(p + 8)
        : "memory");
  }
}

// poll+stage one group-slice of h[t] (16 slots x 16 b x 32 j = 16KB) into LDS.
// BACKOFF: 2 immediate retries, then s_sleep(16) (~1024 cyc) between retries —
// cuts spin-load volume ~10-30x so producer stores aren't queued behind polls.
__device__ __forceinline__ void stage_h(const u16* hexg, u16* HsBuf, int tid, bool fast) {
  const u16* p = hexg + (size_t)tid * 16;
  u32x4 q0, q1;
  ex_load2(p, fast, q0, q1);
  int tries = 0;
  for (;;) {
    u64 a = (u64)q0.x | ((u64)q0.y << 32), b = (u64)q0.z | ((u64)q0.w << 32);
    u64 c = (u64)q1.x | ((u64)q1.y << 32), d = (u64)q1.z | ((u64)q1.w << 32);
    if (!((a == POISON64) | (b == POISON64) | (c == POISON64) | (d == POISON64))) break;
    if (++tries > 2) asm volatile("s_sleep 16");
    ex_load2(p, fast, q0, q1);
  }
  int s2 = tid >> 5, b = (tid >> 1) & 15, half = tid & 1;
  int K0 = s2 * 4 + half * 2;
  *(u32x4*)&HsBuf[b * 512 + ((K0 ^ (b & 7)) << 3)] = q0;
  *(u32x4*)&HsBuf[b * 512 + (((K0 + 1) ^ (b & 7)) << 3)] = q1;
}

// discovery + probe: returns (g, s, fast). Probe exercises the EXACT exchange
// pair used in the loop: atomic-exchange store -> sc0 poll.
__device__ __forceinline__ void group_setup(u32* ctrl, u32* disc_lds, int* fast_shp,
                                            int bid, int tid, int& g, int& s, bool& fast) {
  u32* disc = ctrl; u32* probe = ctrl + 128; u32* ready2 = ctrl + 256; u32* demote = ctrl + 384;
  int w = tid >> 6, lane = tid & 63;
  if (tid == 0) {
    u32 xcd;
    asm volatile("s_getreg_b32 %0, hwreg(HW_REG_XCC_ID)" : "=s"(xcd));
    __hip_atomic_store(&disc[bid], xcd & 7u, __ATOMIC_RELAXED, __HIP_MEMORY_SCOPE_AGENT);
  }
  if (w == 0) {
    const u64* d64 = (const u64*)disc;
    u64 v;
    do { v = __hip_atomic_load(&d64[lane], __ATOMIC_RELAXED, __HIP_MEMORY_SCOPE_AGENT); }
    while ((u32)v == POISON32 || (u32)(v >> 32) == POISON32);
    disc_lds[2 * lane] = (u32)v; disc_lds[2 * lane + 1] = (u32)(v >> 32);
  }
  __syncthreads();
  u64 cnt64 = 0;
  for (int i = 0; i < 128; ++i) cnt64 += 1ULL << ((disc_lds[i] & 7) * 8);
  int myx = (int)(disc_lds[bid] & 7);
  int rank = 0;
  for (int i = 0; i < bid; ++i) if ((int)(disc_lds[i] & 7) == myx) rank++;
  int pre = 0;
  for (int x = 0; x < myx; ++x) pre += (int)((cnt64 >> (x * 8)) & 255);
  int pos = pre + rank;
  g = pos >> 4; s = pos & 15;
  fast = false;
  { int p0 = 0;
    for (int x = 0; x < 8; ++x) { int c = (int)((cnt64 >> (x * 8)) & 255);
      if (p0 <= g * 16 && g * 16 + 16 <= p0 + c) fast = true; p0 += c; } }
  if (fast) {
    if (tid == 0)
      (void)__hip_atomic_exchange(&probe[g * 16 + s], 1u, __ATOMIC_RELAXED,
                                  __HIP_MEMORY_SCOPE_AGENT);
    if (w == 0) {
      bool to = false;
      if (lane < 16) {
        u32 pv = POISON32;
        u64 t0 = memtime();
        for (;;) {
          asm volatile("global_load_dword %0, %1, off sc0\n\ts_waitcnt vmcnt(0)"
                       : "=v"(pv) : "v"(&probe[g * 16 + lane]) : "memory");
          if (pv != POISON32) break;
          if (memtime() - t0 > PROBE_CYCLES) break;
        }
        to = (pv == POISON32);
      }
      if (__any(to) && lane == 0) {
        __hip_atomic_store(&demote[g], 1u, __ATOMIC_RELAXED, __HIP_MEMORY_SCOPE_AGENT);
        asm volatile("s_waitcnt vmcnt(0)" ::: "memory");
      }
    }
    __syncthreads();
    if (tid == 0)
      __hip_atomic_store(&ready2[g * 16 + s], 1u, __ATOMIC_RELAXED, __HIP_MEMORY_SCOPE_AGENT);
    if (w == 0 && lane < 16) {
      u32 rv;
      do { rv = __hip_atomic_load(&ready2[g * 16 + lane], __ATOMIC_RELAXED, __HIP_MEMORY_SCOPE_AGENT); }
      while (rv == POISON32);
    }
    if (tid == 0)
      *fast_shp = (int)(__hip_atomic_load(&demote[g], __ATOMIC_RELAXED, __HIP_MEMORY_SCOPE_AGENT) == 0u);
    __syncthreads();
    fast = (*fast_shp != 0);
  }
}

// ---------------------------------------------------------------------------
// Kernel 1: weight prep, h0 into hex[0], slots 1..T poisoned, ctrl init.
// ---------------------------------------------------------------------------
__global__ __launch_bounds__(256) void prep_kernel(
    const float* __restrict__ enc_h, const float* __restrict__ W_ih,
    const float* __restrict__ W_hh, const float* __restrict__ b_ih,
    const float* __restrict__ b_hh, const float* __restrict__ W_out,
    u16* __restrict__ wih_p, u16* __restrict__ whh_p, u16* __restrict__ wout_b,
    float* __restrict__ bias_p, u16* __restrict__ hex, u32* __restrict__ ctrl) {
  int idx = blockIdx.x * 256 + threadIdx.x;
  int stride = gridDim.x * 256;
  if (idx < 128) { ctrl[idx] = POISON32; ctrl[128 + idx] = POISON32; ctrl[256 + idx] = POISON32; }
  if (idx < 8) ctrl[384 + idx] = 0;
  const int N0 = NG * NE, N1 = NG * NH, N2 = NV * NH, N3 = NG, N4 = NB * NH;
  int total = N0 + N1 + N2 + N3 + N4;
  for (int i = idx; i < total; i += stride) {
    int j = i;
    if (j < N0) {
      int r = j >> 8, k = j & 255;
      int orig = (r & 3) * NH + (r >> 2);
      wih_p[j] = f2bf(W_ih[orig * NE + k]);
    } else if ((j -= N0) < N1) {
      int r = j >> 9, k = j & 511;
      int orig = (r & 3) * NH + (r >> 2);
      whh_p[j] = f2bf(W_hh[orig * NH + k]);
    } else if ((j -= N1) < N2) {
      wout_b[j] = f2bf(W_out[j]);
    } else if ((j -= N2) < N3) {
      int orig = (j & 3) * NH + (j >> 2);
      bias_p[j] = b_ih[orig] + b_hh[orig];
    } else {
      j -= N3;
      int bb = j >> 9, jj = j & 511;
      float v = 0.5f * (enc_h[j] + enc_h[N4 + j]);
      hex[((size_t)(bb >> 4) * 16 + (jj >> 5)) * 512 + (size_t)(bb & 15) * 32 + (jj & 31)] = f2bf(v);
    }
  }
  u64* hp = (u64*)(hex + HEX_T);
  const int NP = NT * (HEX_T / 4);
  for (int i = idx; i < NP; i += stride) hp[i] = POISON64;
}

// ---------------------------------------------------------------------------
// Kernel 2: gates_x = relu(emb[tok]) @ W_ih_p^T + bias_p   -> bf16 (t,b,g')
// ---------------------------------------------------------------------------
__global__ __launch_bounds__(256) void gates_kernel(
    const int* __restrict__ target, const float* __restrict__ emb,
    const u16* __restrict__ wih_p, const float* __restrict__ bias_p,
    u16* __restrict__ gates) {
  __shared__ __align__(16) u16 As[NB * NE];
  int t = blockIdx.y, nTile = blockIdx.x, tid = threadIdx.x;
  for (int i = tid; i < NB * 64; i += 256) {
    int row = i >> 6, c = i & 63;
    int tok = (t == 0) ? 0 : target[row * NT + t - 1];
    float4 f = *(const float4*)(emb + (size_t)tok * NE + c * 4);
    ushort4 pk = make_ushort4(f2bf(fmaxf(f.x, 0.f)), f2bf(fmaxf(f.y, 0.f)),
                              f2bf(fmaxf(f.z, 0.f)), f2bf(fmaxf(f.w, 0.f)));
    int g = c >> 1;
    int off = row * NE + ((((g ^ (row & 7)) << 3)) | ((c & 1) << 2));
    *(ushort4*)&As[off] = pk;
  }
  __syncthreads();
  int w = tid >> 6, lane = tid & 63, l15 = lane & 15, l4 = lane >> 4;
  int mOff = (w & 1) * 64, nOff = (w >> 1) * 64;
  f32x4 acc[4][4] = {};
  for (int kk = 0; kk < 8; ++kk) {
    bf16x8 a[4], bb[4];
    for (int fm = 0; fm < 4; ++fm) {
      int row = mOff + fm * 16 + l15;
      a[fm] = *(const bf16x8*)&As[row * NE + (((kk * 4 + l4) ^ (row & 7)) << 3)];
    }
    int k0 = kk * 32 + l4 * 8;
    for (int fn = 0; fn < 4; ++fn) {
      int n = nTile * 128 + nOff + fn * 16 + l15;
      bb[fn] = *(const bf16x8*)(wih_p + (size_t)n * NE + k0);
    }
    for (int fm = 0; fm < 4; ++fm)
      for (int fn = 0; fn < 4; ++fn)
        acc[fm][fn] = MFMA16(a[fm], bb[fn], acc[fm][fn]);
  }
  for (int fn = 0; fn < 4; ++fn) {
    int n = nTile * 128 + nOff + fn * 16 + l15;
    float bias = bias_p[n];
    for (int fm = 0; fm < 4; ++fm)
      for (int i2 = 0; i2 < 4; ++i2) {
        int row = mOff + fm * 16 + l4 * 4 + i2;
        gates[((size_t)t * NB + row) * NG + n] = f2bf(acc[fm][fn][i2] + bias);
      }
  }
}

// ---------------------------------------------------------------------------
// Kernel 3: LSTM scan. R13 geometry/exchange verbatim; ONE change: poll
// backoff in stage_h (2 immediate retries, then s_sleep between retries).
// ---------------------------------------------------------------------------
__global__ __launch_bounds__(512, 1) void lstm_kernel(
    const float* __restrict__ enc_c, const u16* __restrict__ gates,
    const u16* __restrict__ whh_p, u16* __restrict__ hex,
    float* __restrict__ out_tail, u32* __restrict__ ctrl) {
  __shared__ __align__(16) u16 Hs[2][16 * 512];
  __shared__ u32 disc_lds[128];
  __shared__ int fast_sh;
  int bid = blockIdx.x, tid = threadIdx.x;
  int w = tid >> 6, lane = tid & 63, l15 = lane & 15, l4 = lane >> 4;
  int g, s; bool fast;
  group_setup(ctrl, disc_lds, &fast_sh, bid, tid, g, s, fast);

  bf16x8 wreg[16];
  {
    const u16* wp = whh_p + (size_t)(s * 128 + w * 16 + l15) * NH + l4 * 8;
#pragma unroll
    for (int kk = 0; kk < 16; ++kk) {
      wreg[kk] = *(const bf16x8*)(wp + kk * 32);
      asm volatile("" : "+v"(wreg[kk]));
    }
  }
  int b = g * 16 + l15;
  int j = s * 32 + w * 4 + l4;
  float creg = 0.5f * (enc_c[b * NH + j] + enc_c[NB * NH + b * NH + j]);
  uint2 pg = pf_load_u64(gates + (size_t)b * NG + s * 128 + w * 16 + l4 * 4);
  stage_h(hex + (size_t)g * 8192, &Hs[0][0], tid, fast);
  __syncthreads();
  int cur = 0;

  for (int t = 0; t < NT; ++t) {
    asm volatile("s_waitcnt vmcnt(0)" ::: "memory");
    __builtin_amdgcn_sched_barrier(0);
    f32x4 acc;
    acc[0] = bf2f((u16)(pg.x & 0xFFFF));
    acc[1] = bf2f((u16)(pg.x >> 16));
    acc[2] = bf2f((u16)(pg.y & 0xFFFF));
    acc[3] = bf2f((u16)(pg.y >> 16));
    if (t + 1 < NT)
      pg = pf_load_u64(gates + ((size_t)(t + 1) * NB + b) * NG + s * 128 + w * 16 + l4 * 4);
#pragma unroll
    for (int kk = 0; kk < 16; ++kk) {
      bf16x8 hv = *(const bf16x8*)&Hs[cur][l15 * 512 + (((kk * 4 + l4) ^ (l15 & 7)) << 3)];
      acc = MFMA16(wreg[kk], hv, acc);
    }
    float ig = sigm(acc[0]);
    float fg = sigm(acc[1]);
    float gg = tanh_f(acc[2]);
    float og = sigm(acc[3]);
    float cn = fg * creg + ig * gg;
    creg = cn;
    float hn = og * tanh_f(cn);
    {
      u32 v = (u32)f2bf(hn);
      u32 v2 = (u32)__shfl_xor((int)v, 16, 64);
      v = v | (v2 << 16);
      u32 hi = (u32)__shfl_xor((int)v, 32, 64);
      if (l4 == 0) {
        u64 qv = (u64)v | ((u64)hi << 32);
        u16* hdst = hex + ((size_t)(t + 1) * 8 + g) * 8192;
        ex_store(hdst + ((size_t)s * 16 + l15) * 32 + w * 4, qv);
      }
    }
    if (t == NT - 1) {
      out_tail[b * NH + j] = hn;
      out_tail[NB * NH + b * NH + j] = cn;
      break;
    }
    stage_h(hex + ((size_t)(t + 1) * 8 + g) * 8192, &Hs[cur ^ 1][0], tid, fast);
    __syncthreads();
    cur ^= 1;
  }
}

// ---------------------------------------------------------------------------
// Kernel 4: logits = h[tt+1] @ W_out^T + b_out, reading hex layout directly.
// ---------------------------------------------------------------------------
__global__ __launch_bounds__(256) void logits_kernel(
    const u16* __restrict__ hex, const u16* __restrict__ wout_b,
    const float* __restrict__ b_out, float* __restrict__ out) {
  int tt = blockIdx.y, nTile = blockIdx.x;
  int tid = threadIdx.x, w = tid >> 6, lane = tid & 63, l15 = lane & 15, l4 = lane >> 4;
  int mOff = (w & 1) * 64, nOff = (w >> 1) * 64;
  const u16* A = hex + (size_t)(tt + 1) * HEX_T;
  f32x4 acc[4][4] = {};
  for (int kk = 0; kk < 16; ++kk) {
    int k0 = kk * 32 + l4 * 8;
    bf16x8 a[4], bb[4];
#pragma unroll
    for (int fm = 0; fm < 4; ++fm) {
      int gg = (mOff >> 4) + fm;
      a[fm] = *(const bf16x8*)(A + ((size_t)gg * 16 + kk) * 512 + l15 * 32 + l4 * 8);
    }
#pragma unroll
    for (int fn = 0; fn < 4; ++fn) {
      int v = nTile * 128 + nOff + fn * 16 + l15;
      bb[fn] = *(const bf16x8*)(wout_b + (size_t)v * NH + k0);
    }
    for (int fm = 0; fm < 4; ++fm)
      for (int fn = 0; fn < 4; ++fn)
        acc[fm][fn] = MFMA16(a[fm], bb[fn], acc[fm][fn]);
  }
  for (int fn = 0; fn < 4; ++fn) {
    int v = nTile * 128 + nOff + fn * 16 + l15;
    float bias = b_out[v];
    for (int fm = 0; fm < 4; ++fm)
      for (int i2 = 0; i2 < 4; ++i2) {
        int brow = mOff + fm * 16 + l4 * 4 + i2;
        out[((size_t)brow * NT + tt) * NV + v] = acc[fm][fn][i2] + bias;
      }
  }
}

// ---------------------------------------------------------------------------
// Kernel 5: in-place row log_softmax over V=1024. One wave per row.
// ---------------------------------------------------------------------------
__global__ __launch_bounds__(256) void lsm_kernel(float* __restrict__ out) {
  int row = blockIdx.x * 4 + (threadIdx.x >> 6);
  int lane = threadIdx.x & 63;
  float* p = out + (size_t)row * NV + lane * 4;
  float4 x[4];
  float m = -1e30f;
#pragma unroll
  for (int i = 0; i < 4; ++i) {
    x[i] = *(const float4*)(p + i * 256);
    m = fmaxf(m, fmaxf(fmaxf(x[i].x, x[i].y), fmaxf(x[i].z, x[i].w)));
  }
#pragma unroll
  for (int o = 1; o < 64; o <<= 1) m = fmaxf(m, __shfl_xor(m, o, 64));
  float s = 0.f;
#pragma unroll
  for (int i = 0; i < 4; ++i)
    s += __expf(x[i].x - m) + __expf(x[i].y - m) + __expf(x[i].z - m) + __expf(x[i].w - m);
#pragma unroll
  for (int o = 1; o < 64; o <<= 1) s += __shfl_xor(s, o, 64);
  float lse = m + __logf(s);
#pragma unroll
  for (int i = 0; i < 4; ++i) {
    float4 y = x[i];
    y.x -= lse; y.y -= lse; y.z -= lse; y.w -= lse;
    *(float4*)(p + i * 256) = y;
  }
}

extern "C" void kernel_launch(void* const* d_in, const int* in_sizes, int n_in,
                              void* d_out, int out_size, void* d_ws, size_t ws_size,
                              hipStream_t stream) {
  (void)in_sizes; (void)n_in; (void)out_size; (void)ws_size;
  const float* enc_h  = (const float*)d_in[1];
  const float* enc_c  = (const float*)d_in[2];
  const int*   target = (const int*)d_in[3];
  const float* emb    = (const float*)d_in[4];
  const float* W_ih   = (const float*)d_in[5];
  const float* W_hh   = (const float*)d_in[6];
  const float* b_ih   = (const float*)d_in[7];
  const float* b_hh   = (const float*)d_in[8];
  const float* W_out  = (const float*)d_in[9];
  const float* b_out  = (const float*)d_in[10];

  char* ws = (char*)d_ws;
  u16*   wih_p  = (u16*)(ws);                  // 2048x256 bf16   (1 MB)
  u16*   whh_p  = (u16*)(ws + (1 << 20));      // 2048x512 bf16   (2 MB)
  u16*   wout_b = (u16*)(ws + (3 << 20));      // 1024x512 bf16   (1 MB)
  float* bias_p = (float*)(ws + (4 << 20));    // 2048 f32
  u32*   ctrl   = (u32*)(ws + (4 << 20) + 8192);   // discovery/probe block
  u16*   hex    = (u16*)(ws + (4 << 20) + 16384);  // (T+1) x 65536 bf16 (67.2 MB)

  u16*   gates  = (u16*)d_out;                       // 268 MB bf16, aliases log_probs
  float* out    = (float*)d_out;
  float* out_tail = out + (size_t)NB * NT * NV;      // h_T then c_T

  prep_kernel<<<dim3(2048), 256, 0, stream>>>(enc_h, W_ih, W_hh, b_ih, b_hh, W_out,
                                              wih_p, whh_p, wout_b, bias_p, hex, ctrl);
  gates_kernel<<<dim3(16, 512), 256, 0, stream>>>(target, emb, wih_p, bias_p, gates);
  {
    const float* enc_c_a = enc_c;
    const u16* gates_a = gates;
    const u16* whh_a = whh_p;
    u16* hex_a = hex;
    float* tail_a = out_tail;
    u32* ctrl_a = ctrl;
    void* args[] = {&enc_c_a, &gates_a, &whh_a, &hex_a, &tail_a, &ctrl_a};
    hipLaunchCooperativeKernel((const void*)lstm_kernel, dim3(128), dim3(512),
                               args, 0, stream);
  }
  logits_kernel<<<dim3(8, 512), 256, 0, stream>>>(hex, wout_b, b_out, out);
  lsm_kernel<<<16384, 256, 0, stream>>>(out);
}

// Round 15
// 3986.587 us; speedup vs baseline: 1.0195x; 1.0195x over previous
//
#include <hip/hip_runtime.h>

typedef unsigned short u16;
typedef unsigned int u32;
typedef unsigned long long u64;
typedef short bf16x8 __attribute__((ext_vector_type(8)));
typedef float f32x4 __attribute__((ext_vector_type(4)));
typedef unsigned u32x4 __attribute__((ext_vector_type(4)));

#define NB 128
#define NT 512
#define NV 1024
#define NE 256
#define NH 512
#define NG 2048

#define POISON64 0xFFFFFFFFFFFFFFFFULL
#define POISON32 0xFFFFFFFFu
#define HEX_T 65536  // elements per t-slot: 8 groups x 16 slots x 16 b x 32 j
#define PROBE_CYCLES 480000ULL  // ~0.2 ms @ 2.4 GHz

__device__ __forceinline__ u16 f2bf(float f) {
  union { float f; unsigned u; } v; v.f = f;
  unsigned r = v.u + 0x7FFFu + ((v.u >> 16) & 1u);
  return (u16)(r >> 16);
}
__device__ __forceinline__ float bf2f(u16 u) {
  union { unsigned u; float f; } v; v.u = ((unsigned)u) << 16;
  return v.f;
}
__device__ __forceinline__ float sigm(float x) { return 1.f / (1.f + __expf(-x)); }
__device__ __forceinline__ float tanh_f(float x) {
  x = fminf(fmaxf(x, -20.f), 20.f);
  float e = __expf(2.f * x);
  return (e - 1.f) / (e + 1.f);
}
__device__ __forceinline__ u64 memtime() {
  u64 t;
  asm volatile("s_memtime %0\n\ts_waitcnt lgkmcnt(0)" : "=s"(t));
  return t;
}

#define MFMA16(a, b, c) __builtin_amdgcn_mfma_f32_16x16x32_bf16((a), (b), (c), 0, 0, 0)

__device__ __forceinline__ u64 dc_load_u64(const void* p) {
  return __hip_atomic_load((const u64*)p, __ATOMIC_RELAXED, __HIP_MEMORY_SCOPE_AGENT);
}
// plain cached prefetch load (gates stream)
__device__ __forceinline__ uint2 pf_load_u64(const void* p) {
  uint2 r;
  asm volatile("global_load_dwordx2 %0, %1, off" : "=v"(r) : "v"(p) : "memory");
  return r;
}
// exchange store: ATOMIC exchange (R13-proven; executes at coherence point)
__device__ __forceinline__ void ex_store(u16* p, u64 v) {
  (void)__hip_atomic_exchange((u64*)p, v, __ATOMIC_RELAXED, __HIP_MEMORY_SCOPE_AGENT);
}
// exchange/poll load of 32B. fast: sc0 only -> L2-served. slow: sc0 sc1 -> L3.
__device__ __forceinline__ void ex_load2(const u16* p, bool fast, u32x4& q0, u32x4& q1) {
  if (fast) {
    asm volatile(
        "global_load_dwordx4 %0, %2, off sc0\n\t"
        "global_load_dwordx4 %1, %3, off sc0\n\t"
        "s_waitcnt vmcnt(0)"
        : "=&v"(q0), "=&v"(q1)
        : "v"(p), "v"(p + 8)
        : "memory");
  } else {
    asm volatile(
        "global_load_dwordx4 %0, %2, off sc0 sc1\n\t"
        "global_load_dwordx4 %1, %3, off sc0 sc1\n\t"
        "s_waitcnt vmcnt(0)"
        : "=&v"(q0), "=&v"(q1)
        : "v"(p), "v"(p + 8)
        : "memory");
  }
}

// lstm poll+stage one group-slice of h[t] (16KB) into LDS (R13-exact).
__device__ __forceinline__ void stage_h(const u16* hexg, u16* HsBuf, int tid, bool fast) {
  const u16* p = hexg + (size_t)tid * 16;
  u32x4 q0, q1;
  ex_load2(p, fast, q0, q1);
  for (;;) {
    u64 a = (u64)q0.x | ((u64)q0.y << 32), b = (u64)q0.z | ((u64)q0.w << 32);
    u64 c = (u64)q1.x | ((u64)q1.y << 32), d = (u64)q1.z | ((u64)q1.w << 32);
    if (!((a == POISON64) | (b == POISON64) | (c == POISON64) | (d == POISON64))) break;
    ex_load2(p, fast, q0, q1);
  }
  int s2 = tid >> 5, b = (tid >> 1) & 15, half = tid & 1;
  int K0 = s2 * 4 + half * 2;
  *(u32x4*)&HsBuf[b * 512 + ((K0 ^ (b & 7)) << 3)] = q0;
  *(u32x4*)&HsBuf[b * 512 + (((K0 + 1) ^ (b & 7)) << 3)] = q1;
}

// worker: poll one 16B A-frag (2 producer granules) via agent loads + sleep.
__device__ __forceinline__ bf16x8 w_poll_frag(const u16* p) {
  u64 lo = dc_load_u64(p), hi = dc_load_u64(p + 4);
  while (lo == POISON64 || hi == POISON64) {
    asm volatile("s_sleep 64");
    lo = dc_load_u64(p); hi = dc_load_u64(p + 4);
  }
  u32x4 q = {(u32)lo, (u32)(lo >> 32), (u32)hi, (u32)(hi >> 32)};
  return __builtin_bit_cast(bf16x8, q);
}

// discovery + probe (R13-exact): returns (g, s, fast) for lstm WGs.
__device__ __forceinline__ void group_setup(u32* ctrl, u32* disc_lds, int* fast_shp,
                                            int bid, int tid, int& g, int& s, bool& fast) {
  u32* disc = ctrl; u32* probe = ctrl + 128; u32* ready2 = ctrl + 256; u32* demote = ctrl + 384;
  int w = tid >> 6, lane = tid & 63;
  if (tid == 0) {
    u32 xcd;
    asm volatile("s_getreg_b32 %0, hwreg(HW_REG_XCC_ID)" : "=s"(xcd));
    __hip_atomic_store(&disc[bid], xcd & 7u, __ATOMIC_RELAXED, __HIP_MEMORY_SCOPE_AGENT);
  }
  if (w == 0) {
    const u64* d64 = (const u64*)disc;
    u64 v;
    do { v = __hip_atomic_load(&d64[lane], __ATOMIC_RELAXED, __HIP_MEMORY_SCOPE_AGENT); }
    while ((u32)v == POISON32 || (u32)(v >> 32) == POISON32);
    disc_lds[2 * lane] = (u32)v; disc_lds[2 * lane + 1] = (u32)(v >> 32);
  }
  __syncthreads();
  u64 cnt64 = 0;
  for (int i = 0; i < 128; ++i) cnt64 += 1ULL << ((disc_lds[i] & 7) * 8);
  int myx = (int)(disc_lds[bid] & 7);
  int rank = 0;
  for (int i = 0; i < bid; ++i) if ((int)(disc_lds[i] & 7) == myx) rank++;
  int pre = 0;
  for (int x = 0; x < myx; ++x) pre += (int)((cnt64 >> (x * 8)) & 255);
  int pos = pre + rank;
  g = pos >> 4; s = pos & 15;
  fast = false;
  { int p0 = 0;
    for (int x = 0; x < 8; ++x) { int c = (int)((cnt64 >> (x * 8)) & 255);
      if (p0 <= g * 16 && g * 16 + 16 <= p0 + c) fast = true; p0 += c; } }
  if (fast) {
    if (tid == 0)
      (void)__hip_atomic_exchange(&probe[g * 16 + s], 1u, __ATOMIC_RELAXED,
                                  __HIP_MEMORY_SCOPE_AGENT);
    if (w == 0) {
      bool to = false;
      if (lane < 16) {
        u32 pv = POISON32;
        u64 t0 = memtime();
        for (;;) {
          asm volatile("global_load_dword %0, %1, off sc0\n\ts_waitcnt vmcnt(0)"
                       : "=v"(pv) : "v"(&probe[g * 16 + lane]) : "memory");
          if (pv != POISON32) break;
          if (memtime() - t0 > PROBE_CYCLES) break;
        }
        to = (pv == POISON32);
      }
      if (__any(to) && lane == 0) {
        __hip_atomic_store(&demote[g], 1u, __ATOMIC_RELAXED, __HIP_MEMORY_SCOPE_AGENT);
        asm volatile("s_waitcnt vmcnt(0)" ::: "memory");
      }
    }
    __syncthreads();
    if (tid == 0)
      __hip_atomic_store(&ready2[g * 16 + s], 1u, __ATOMIC_RELAXED, __HIP_MEMORY_SCOPE_AGENT);
    if (w == 0 && lane < 16) {
      u32 rv;
      do { rv = __hip_atomic_load(&ready2[g * 16 + lane], __ATOMIC_RELAXED, __HIP_MEMORY_SCOPE_AGENT); }
      while (rv == POISON32);
    }
    if (tid == 0)
      *fast_shp = (int)(__hip_atomic_load(&demote[g], __ATOMIC_RELAXED, __HIP_MEMORY_SCOPE_AGENT) == 0u);
    __syncthreads();
    fast = (*fast_shp != 0);
  }
}

// ---------------------------------------------------------------------------
// Kernel 1: weight prep, h0 into hex[0], slots 1..T poisoned, ctrl init.
// ---------------------------------------------------------------------------
__global__ __launch_bounds__(256) void prep_kernel(
    const float* __restrict__ enc_h, const float* __restrict__ W_ih,
    const float* __restrict__ W_hh, const float* __restrict__ b_ih,
    const float* __restrict__ b_hh, const float* __restrict__ W_out,
    u16* __restrict__ wih_p, u16* __restrict__ whh_p, u16* __restrict__ wout_b,
    float* __restrict__ bias_p, u16* __restrict__ hex, u32* __restrict__ ctrl) {
  int idx = blockIdx.x * 256 + threadIdx.x;
  int stride = gridDim.x * 256;
  if (idx < 128) { ctrl[idx] = POISON32; ctrl[128 + idx] = POISON32; ctrl[256 + idx] = POISON32; }
  if (idx < 8) ctrl[384 + idx] = 0;
  const int N0 = NG * NE, N1 = NG * NH, N2 = NV * NH, N3 = NG, N4 = NB * NH;
  int total = N0 + N1 + N2 + N3 + N4;
  for (int i = idx; i < total; i += stride) {
    int j = i;
    if (j < N0) {
      int r = j >> 8, k = j & 255;
      int orig = (r & 3) * NH + (r >> 2);
      wih_p[j] = f2bf(W_ih[orig * NE + k]);
    } else if ((j -= N0) < N1) {
      int r = j >> 9, k = j & 511;
      int orig = (r & 3) * NH + (r >> 2);
      whh_p[j] = f2bf(W_hh[orig * NH + k]);
    } else if ((j -= N1) < N2) {
      wout_b[j] = f2bf(W_out[j]);
    } else if ((j -= N2) < N3) {
      int orig = (j & 3) * NH + (j >> 2);
      bias_p[j] = b_ih[orig] + b_hh[orig];
    } else {
      j -= N3;
      int bb = j >> 9, jj = j & 511;
      float v = 0.5f * (enc_h[j] + enc_h[N4 + j]);
      hex[((size_t)(bb >> 4) * 16 + (jj >> 5)) * 512 + (size_t)(bb & 15) * 32 + (jj & 31)] = f2bf(v);
    }
  }
  u64* hp = (u64*)(hex + HEX_T);
  const int NP = NT * (HEX_T / 4);
  for (int i = idx; i < NP; i += stride) hp[i] = POISON64;
}

// ---------------------------------------------------------------------------
// Kernel 2: gates_x -> bf16, NEW layout (b, t, n): one gate-row (t,b) = 4KB,
// byte-exact with out-block (b,t) so workers can safely overwrite consumed rows.
// ---------------------------------------------------------------------------
__global__ __launch_bounds__(256) void gates_kernel(
    const int* __restrict__ target, const float* __restrict__ emb,
    const u16* __restrict__ wih_p, const float* __restrict__ bias_p,
    u16* __restrict__ gates) {
  __shared__ __align__(16) u16 As[NB * NE];
  int t = blockIdx.y, nTile = blockIdx.x, tid = threadIdx.x;
  for (int i = tid; i < NB * 64; i += 256) {
    int row = i >> 6, c = i & 63;
    int tok = (t == 0) ? 0 : target[row * NT + t - 1];
    float4 f = *(const float4*)(emb + (size_t)tok * NE + c * 4);
    ushort4 pk = make_ushort4(f2bf(fmaxf(f.x, 0.f)), f2bf(fmaxf(f.y, 0.f)),
                              f2bf(fmaxf(f.z, 0.f)), f2bf(fmaxf(f.w, 0.f)));
    int g = c >> 1;
    int off = row * NE + ((((g ^ (row & 7)) << 3)) | ((c & 1) << 2));
    *(ushort4*)&As[off] = pk;
  }
  __syncthreads();
  int w = tid >> 6, lane = tid & 63, l15 = lane & 15, l4 = lane >> 4;
  int mOff = (w & 1) * 64, nOff = (w >> 1) * 64;
  f32x4 acc[4][4] = {};
  for (int kk = 0; kk < 8; ++kk) {
    bf16x8 a[4], bb[4];
    for (int fm = 0; fm < 4; ++fm) {
      int row = mOff + fm * 16 + l15;
      a[fm] = *(const bf16x8*)&As[row * NE + (((kk * 4 + l4) ^ (row & 7)) << 3)];
    }
    int k0 = kk * 32 + l4 * 8;
    for (int fn = 0; fn < 4; ++fn) {
      int n = nTile * 128 + nOff + fn * 16 + l15;
      bb[fn] = *(const bf16x8*)(wih_p + (size_t)n * NE + k0);
    }
    for (int fm = 0; fm < 4; ++fm)
      for (int fn = 0; fn < 4; ++fn)
        acc[fm][fn] = MFMA16(a[fm], bb[fn], acc[fm][fn]);
  }
  for (int fn = 0; fn < 4; ++fn) {
    int n = nTile * 128 + nOff + fn * 16 + l15;
    float bias = bias_p[n];
    for (int fm = 0; fm < 4; ++fm)
      for (int i2 = 0; i2 < 4; ++i2) {
        int row = mOff + fm * 16 + l4 * 4 + i2;
        gates[((size_t)row * NT + t) * NG + n] = f2bf(acc[fm][fn][i2] + bias);
      }
  }
}

// ---------------------------------------------------------------------------
// Kernel 3 (MEGA, cooperative, 256 WGs x 512 thr):
//  WGs 0-127:  LSTM scan (R13-exact; gates reads use the (b,t,n) layout).
//  WGs 128-255: logits workers — poison-poll hex[tt+1] (agent loads + sleep,
//  latency-tolerant) and write raw logits+bias fp32 into d_out. Safe: worker's
//  poll of h[tt+1] certifies group b>>4 finished step tt, so gates row (tt,b)
//  (same bytes as out-block (b,tt)) is dead before the overwrite.
// ---------------------------------------------------------------------------
__global__ __launch_bounds__(512, 2) void mega_kernel(
    const float* __restrict__ enc_c, const u16* __restrict__ gates,
    const u16* __restrict__ whh_p, u16* __restrict__ hex,
    float* __restrict__ out_tail, u32* __restrict__ ctrl,
    const u16* __restrict__ wout_b, const float* __restrict__ b_out,
    float* __restrict__ out) {
  __shared__ __align__(16) u16 Hs[2][16 * 512];
  __shared__ u32 disc_lds[128];
  __shared__ int fast_sh;
  int bid = blockIdx.x, tid = threadIdx.x;
  int w = tid >> 6, lane = tid & 63, l15 = lane & 15, l4 = lane >> 4;

  if (bid < 128) {
    // ------------------------- LSTM scan (R13) -------------------------
    int g, s; bool fast;
    group_setup(ctrl, disc_lds, &fast_sh, bid, tid, g, s, fast);

    bf16x8 wreg[16];
    {
      const u16* wp = whh_p + (size_t)(s * 128 + w * 16 + l15) * NH + l4 * 8;
#pragma unroll
      for (int kk = 0; kk < 16; ++kk) {
        wreg[kk] = *(const bf16x8*)(wp + kk * 32);
        asm volatile("" : "+v"(wreg[kk]));
      }
    }
    int b = g * 16 + l15;
    int j = s * 32 + w * 4 + l4;
    float creg = 0.5f * (enc_c[b * NH + j] + enc_c[NB * NH + b * NH + j]);
    uint2 pg = pf_load_u64(gates + ((size_t)b * NT + 0) * NG + s * 128 + w * 16 + l4 * 4);
    stage_h(hex + (size_t)g * 8192, &Hs[0][0], tid, fast);
    __syncthreads();
    int cur = 0;

    for (int t = 0; t < NT; ++t) {
      asm volatile("s_waitcnt vmcnt(0)" ::: "memory");
      __builtin_amdgcn_sched_barrier(0);
      f32x4 acc;
      acc[0] = bf2f((u16)(pg.x & 0xFFFF));
      acc[1] = bf2f((u16)(pg.x >> 16));
      acc[2] = bf2f((u16)(pg.y & 0xFFFF));
      acc[3] = bf2f((u16)(pg.y >> 16));
      if (t + 1 < NT)
        pg = pf_load_u64(gates + ((size_t)b * NT + (t + 1)) * NG + s * 128 + w * 16 + l4 * 4);
#pragma unroll
      for (int kk = 0; kk < 16; ++kk) {
        bf16x8 hv = *(const bf16x8*)&Hs[cur][l15 * 512 + (((kk * 4 + l4) ^ (l15 & 7)) << 3)];
        acc = MFMA16(wreg[kk], hv, acc);
      }
      float ig = sigm(acc[0]);
      float fg = sigm(acc[1]);
      float gg = tanh_f(acc[2]);
      float og = sigm(acc[3]);
      float cn = fg * creg + ig * gg;
      creg = cn;
      float hn = og * tanh_f(cn);
      {
        u32 v = (u32)f2bf(hn);
        u32 v2 = (u32)__shfl_xor((int)v, 16, 64);
        v = v | (v2 << 16);
        u32 hi = (u32)__shfl_xor((int)v, 32, 64);
        if (l4 == 0) {
          u64 qv = (u64)v | ((u64)hi << 32);
          u16* hdst = hex + ((size_t)(t + 1) * 8 + g) * 8192;
          ex_store(hdst + ((size_t)s * 16 + l15) * 32 + w * 4, qv);
        }
      }
      if (t == NT - 1) {
        out_tail[b * NH + j] = hn;
        out_tail[NB * NH + b * NH + j] = cn;
        break;
      }
      stage_h(hex + ((size_t)(t + 1) * 8 + g) * 8192, &Hs[cur ^ 1][0], tid, fast);
      __syncthreads();
      cur ^= 1;
    }
  } else {
    // ------------------------- logits workers -------------------------
    int wid = bid - 128;
#pragma unroll 1
    for (int rep = 0; rep < 4; ++rep) {
      int tt = wid + rep * 128;
      const u16* A = hex + (size_t)(tt + 1) * HEX_T;
#pragma unroll 1
      for (int mh = 0; mh < 2; ++mh) {
        f32x4 acc[2][4][4] = {};
#pragma unroll 1
        for (int kk = 0; kk < 16; ++kk) {
          bf16x8 a[4];
#pragma unroll
          for (int fm = 0; fm < 4; ++fm)
            a[fm] = w_poll_frag(A + (((size_t)(mh * 4 + fm) * 16 + kk) * 512 + l15 * 32 + l4 * 8));
          bf16x8 bb[2][4];
#pragma unroll
          for (int np = 0; np < 2; ++np)
#pragma unroll
            for (int fn = 0; fn < 4; ++fn)
              bb[np][fn] = *(const bf16x8*)(wout_b +
                  (size_t)(np * 512 + w * 64 + fn * 16 + l15) * NH + kk * 32 + l4 * 8);
#pragma unroll
          for (int np = 0; np < 2; ++np)
#pragma unroll
            for (int fm = 0; fm < 4; ++fm)
#pragma unroll
              for (int fn = 0; fn < 4; ++fn)
                acc[np][fm][fn] = MFMA16(a[fm], bb[np][fn], acc[np][fm][fn]);
        }
#pragma unroll
        for (int np = 0; np < 2; ++np)
#pragma unroll
          for (int fn = 0; fn < 4; ++fn) {
            int v = np * 512 + w * 64 + fn * 16 + l15;
            float bias = b_out[v];
#pragma unroll
            for (int fm = 0; fm < 4; ++fm)
#pragma unroll
              for (int i2 = 0; i2 < 4; ++i2) {
                int m = mh * 64 + fm * 16 + l4 * 4 + i2;
                out[((size_t)m * NT + tt) * NV + v] = acc[np][fm][fn][i2] + bias;
              }
          }
      }
    }
  }
}

// ---------------------------------------------------------------------------
// Kernel 5: in-place row log_softmax over V=1024. One wave per row.
// ---------------------------------------------------------------------------
__global__ __launch_bounds__(256) void lsm_kernel(float* __restrict__ out) {
  int row = blockIdx.x * 4 + (threadIdx.x >> 6);
  int lane = threadIdx.x & 63;
  float* p = out + (size_t)row * NV + lane * 4;
  float4 x[4];
  float m = -1e30f;
#pragma unroll
  for (int i = 0; i < 4; ++i) {
    x[i] = *(const float4*)(p + i * 256);
    m = fmaxf(m, fmaxf(fmaxf(x[i].x, x[i].y), fmaxf(x[i].z, x[i].w)));
  }
#pragma unroll
  for (int o = 1; o < 64; o <<= 1) m = fmaxf(m, __shfl_xor(m, o, 64));
  float s = 0.f;
#pragma unroll
  for (int i = 0; i < 4; ++i)
    s += __expf(x[i].x - m) + __expf(x[i].y - m) + __expf(x[i].z - m) + __expf(x[i].w - m);
#pragma unroll
  for (int o = 1; o < 64; o <<= 1) s += __shfl_xor(s, o, 64);
  float lse = m + __logf(s);
#pragma unroll
  for (int i = 0; i < 4; ++i) {
    float4 y = x[i];
    y.x -= lse; y.y -= lse; y.z -= lse; y.w -= lse;
    *(float4*)(p + i * 256) = y;
  }
}

extern "C" void kernel_launch(void* const* d_in, const int* in_sizes, int n_in,
                              void* d_out, int out_size, void* d_ws, size_t ws_size,
                              hipStream_t stream) {
  (void)in_sizes; (void)n_in; (void)out_size; (void)ws_size;
  const float* enc_h  = (const float*)d_in[1];
  const float* enc_c  = (const float*)d_in[2];
  const int*   target = (const int*)d_in[3];
  const float* emb    = (const float*)d_in[4];
  const float* W_ih   = (const float*)d_in[5];
  const float* W_hh   = (const float*)d_in[6];
  const float* b_ih   = (const float*)d_in[7];
  const float* b_hh   = (const float*)d_in[8];
  const float* W_out  = (const float*)d_in[9];
  const float* b_out  = (const float*)d_in[10];

  char* ws = (char*)d_ws;
  u16*   wih_p  = (u16*)(ws);                  // 2048x256 bf16   (1 MB)
  u16*   whh_p  = (u16*)(ws + (1 << 20));      // 2048x512 bf16   (2 MB)
  u16*   wout_b = (u16*)(ws + (3 << 20));      // 1024x512 bf16   (1 MB)
  float* bias_p = (float*)(ws + (4 << 20));    // 2048 f32
  u32*   ctrl   = (u32*)(ws + (4 << 20) + 8192);   // discovery/probe block
  u16*   hex    = (u16*)(ws + (4 << 20) + 16384);  // (T+1) x 65536 bf16 (67.2 MB)

  u16*   gates  = (u16*)d_out;                       // 268 MB bf16 (b,t,n), aliases out
  float* out    = (float*)d_out;
  float* out_tail = out + (size_t)NB * NT * NV;      // h_T then c_T

  prep_kernel<<<dim3(2048), 256, 0, stream>>>(enc_h, W_ih, W_hh, b_ih, b_hh, W_out,
                                              wih_p, whh_p, wout_b, bias_p, hex, ctrl);
  gates_kernel<<<dim3(16, 512), 256, 0, stream>>>(target, emb, wih_p, bias_p, gates);
  {
    const float* enc_c_a = enc_c;
    const u16* gates_a = gates;
    const u16* whh_a = whh_p;
    u16* hex_a = hex;
    float* tail_a = out_tail;
    u32* ctrl_a = ctrl;
    const u16* woutb_a = wout_b;
    const float* bout_a = b_out;
    float* out_a = out;
    void* args[] = {&enc_c_a, &gates_a, &whh_a, &hex_a, &tail_a, &ctrl_a,
                    &woutb_a, &bout_a, &out_a};
    hipLaunchCooperativeKernel((const void*)mega_kernel, dim3(256), dim3(512),
                               args, 0, stream);
  }
  lsm_kernel<<<16384, 256, 0, stream>>>(out);
}

// Round 16
// 3645.327 us; speedup vs baseline: 1.1149x; 1.0936x over previous
//
#include <hip/hip_runtime.h>

typedef unsigned short u16;
typedef unsigned int u32;
typedef unsigned long long u64;
typedef short bf16x8 __attribute__((ext_vector_type(8)));
typedef float f32x4 __attribute__((ext_vector_type(4)));
typedef unsigned u32x4 __attribute__((ext_vector_type(4)));

#define NB 128
#define NT 512
#define NV 1024
#define NE 256
#define NH 512
#define NG 2048

#define POISON64 0xFFFFFFFFFFFFFFFFULL
#define POISON32 0xFFFFFFFFu
#define HEX_T 65536  // elements per t-slot: 8 groups x 16 slots x 16 b x 32 j
#define PROBE_CYCLES 480000ULL  // ~0.2 ms @ 2.4 GHz

__device__ __forceinline__ u16 f2bf(float f) {
  union { float f; unsigned u; } v; v.f = f;
  unsigned r = v.u + 0x7FFFu + ((v.u >> 16) & 1u);
  return (u16)(r >> 16);
}
__device__ __forceinline__ float bf2f(u16 u) {
  union { unsigned u; float f; } v; v.u = ((unsigned)u) << 16;
  return v.f;
}
__device__ __forceinline__ float sigm(float x) { return 1.f / (1.f + __expf(-x)); }
__device__ __forceinline__ float tanh_f(float x) {
  x = fminf(fmaxf(x, -20.f), 20.f);
  float e = __expf(2.f * x);
  return (e - 1.f) / (e + 1.f);
}
__device__ __forceinline__ u64 memtime() {
  u64 t;
  asm volatile("s_memtime %0\n\ts_waitcnt lgkmcnt(0)" : "=s"(t));
  return t;
}

#define MFMA16(a, b, c) __builtin_amdgcn_mfma_f32_16x16x32_bf16((a), (b), (c), 0, 0, 0)

__device__ __forceinline__ u64 dc_load_u64(const void* p) {
  return __hip_atomic_load((const u64*)p, __ATOMIC_RELAXED, __HIP_MEMORY_SCOPE_AGENT);
}
// gate-stream load: sc0 sc1 (L3-coherent, cross-XCD worker->scan), no waitcnt
__device__ __forceinline__ uint2 g_load_u64(const void* p) {
  uint2 r;
  asm volatile("global_load_dwordx2 %0, %1, off sc0 sc1" : "=v"(r) : "v"(p) : "memory");
  return r;
}
// exchange store: ATOMIC exchange (R13-proven; executes at coherence point)
__device__ __forceinline__ void ex_store(u16* p, u64 v) {
  (void)__hip_atomic_exchange((u64*)p, v, __ATOMIC_RELAXED, __HIP_MEMORY_SCOPE_AGENT);
}
// visible 8B store for worker-produced gates (R8-proven globally visible)
__device__ __forceinline__ void g_store_u64(u16* p, u64 v) {
  asm volatile("global_store_dwordx2 %0, %1, off sc0 sc1" :: "v"(p), "v"(v) : "memory");
}
// exchange/poll load of 32B. fast: sc0 only -> L2-served. slow: sc0 sc1 -> L3.
__device__ __forceinline__ void ex_load2(const u16* p, bool fast, u32x4& q0, u32x4& q1) {
  if (fast) {
    asm volatile(
        "global_load_dwordx4 %0, %2, off sc0\n\t"
        "global_load_dwordx4 %1, %3, off sc0\n\t"
        "s_waitcnt vmcnt(0)"
        : "=&v"(q0), "=&v"(q1)
        : "v"(p), "v"(p + 8)
        : "memory");
  } else {
    asm volatile(
        "global_load_dwordx4 %0, %2, off sc0 sc1\n\t"
        "global_load_dwordx4 %1, %3, off sc0 sc1\n\t"
        "s_waitcnt vmcnt(0)"
        : "=&v"(q0), "=&v"(q1)
        : "v"(p), "v"(p + 8)
        : "memory");
  }
}

// lstm poll+stage one group-slice of h[t] (16KB) into LDS (R13-exact).
__device__ __forceinline__ void stage_h(const u16* hexg, u16* HsBuf, int tid, bool fast) {
  const u16* p = hexg + (size_t)tid * 16;
  u32x4 q0, q1;
  ex_load2(p, fast, q0, q1);
  for (;;) {
    u64 a = (u64)q0.x | ((u64)q0.y << 32), b = (u64)q0.z | ((u64)q0.w << 32);
    u64 c = (u64)q1.x | ((u64)q1.y << 32), d = (u64)q1.z | ((u64)q1.w << 32);
    if (!((a == POISON64) | (b == POISON64) | (c == POISON64) | (d == POISON64))) break;
    ex_load2(p, fast, q0, q1);
  }
  int s2 = tid >> 5, b = (tid >> 1) & 15, half = tid & 1;
  int K0 = s2 * 4 + half * 2;
  *(u32x4*)&HsBuf[b * 512 + ((K0 ^ (b & 7)) << 3)] = q0;
  *(u32x4*)&HsBuf[b * 512 + (((K0 + 1) ^ (b & 7)) << 3)] = q1;
}

// worker: poll one 16B A-frag (2 producer granules) via agent loads + sleep.
__device__ __forceinline__ bf16x8 w_poll_frag(const u16* p) {
  u64 lo = dc_load_u64(p), hi = dc_load_u64(p + 4);
  while (lo == POISON64 || hi == POISON64) {
    asm volatile("s_sleep 64");
    lo = dc_load_u64(p); hi = dc_load_u64(p + 4);
  }
  u32x4 q = {(u32)lo, (u32)(lo >> 32), (u32)hi, (u32)(hi >> 32)};
  return __builtin_bit_cast(bf16x8, q);
}

// discovery + probe (R13-exact): returns (g, s, fast) for lstm WGs.
__device__ __forceinline__ void group_setup(u32* ctrl, u32* disc_lds, int* fast_shp,
                                            int bid, int tid, int& g, int& s, bool& fast) {
  u32* disc = ctrl; u32* probe = ctrl + 128; u32* ready2 = ctrl + 256; u32* demote = ctrl + 384;
  int w = tid >> 6, lane = tid & 63;
  if (tid == 0) {
    u32 xcd;
    asm volatile("s_getreg_b32 %0, hwreg(HW_REG_XCC_ID)" : "=s"(xcd));
    __hip_atomic_store(&disc[bid], xcd & 7u, __ATOMIC_RELAXED, __HIP_MEMORY_SCOPE_AGENT);
  }
  if (w == 0) {
    const u64* d64 = (const u64*)disc;
    u64 v;
    do { v = __hip_atomic_load(&d64[lane], __ATOMIC_RELAXED, __HIP_MEMORY_SCOPE_AGENT); }
    while ((u32)v == POISON32 || (u32)(v >> 32) == POISON32);
    disc_lds[2 * lane] = (u32)v; disc_lds[2 * lane + 1] = (u32)(v >> 32);
  }
  __syncthreads();
  u64 cnt64 = 0;
  for (int i = 0; i < 128; ++i) cnt64 += 1ULL << ((disc_lds[i] & 7) * 8);
  int myx = (int)(disc_lds[bid] & 7);
  int rank = 0;
  for (int i = 0; i < bid; ++i) if ((int)(disc_lds[i] & 7) == myx) rank++;
  int pre = 0;
  for (int x = 0; x < myx; ++x) pre += (int)((cnt64 >> (x * 8)) & 255);
  int pos = pre + rank;
  g = pos >> 4; s = pos & 15;
  fast = false;
  { int p0 = 0;
    for (int x = 0; x < 8; ++x) { int c = (int)((cnt64 >> (x * 8)) & 255);
      if (p0 <= g * 16 && g * 16 + 16 <= p0 + c) fast = true; p0 += c; } }
  if (fast) {
    if (tid == 0)
      (void)__hip_atomic_exchange(&probe[g * 16 + s], 1u, __ATOMIC_RELAXED,
                                  __HIP_MEMORY_SCOPE_AGENT);
    if (w == 0) {
      bool to = false;
      if (lane < 16) {
        u32 pv = POISON32;
        u64 t0 = memtime();
        for (;;) {
          asm volatile("global_load_dword %0, %1, off sc0\n\ts_waitcnt vmcnt(0)"
                       : "=v"(pv) : "v"(&probe[g * 16 + lane]) : "memory");
          if (pv != POISON32) break;
          if (memtime() - t0 > PROBE_CYCLES) break;
        }
        to = (pv == POISON32);
      }
      if (__any(to) && lane == 0) {
        __hip_atomic_store(&demote[g], 1u, __ATOMIC_RELAXED, __HIP_MEMORY_SCOPE_AGENT);
        asm volatile("s_waitcnt vmcnt(0)" ::: "memory");
      }
    }
    __syncthreads();
    if (tid == 0)
      __hip_atomic_store(&ready2[g * 16 + s], 1u, __ATOMIC_RELAXED, __HIP_MEMORY_SCOPE_AGENT);
    if (w == 0 && lane < 16) {
      u32 rv;
      do { rv = __hip_atomic_load(&ready2[g * 16 + lane], __ATOMIC_RELAXED, __HIP_MEMORY_SCOPE_AGENT); }
      while (rv == POISON32);
    }
    if (tid == 0)
      *fast_shp = (int)(__hip_atomic_load(&demote[g], __ATOMIC_RELAXED, __HIP_MEMORY_SCOPE_AGENT) == 0u);
    __syncthreads();
    fast = (*fast_shp != 0);
  }
}

// ---------------------------------------------------------------------------
// Kernel 1: weight prep, relu'd bf16 embedding table, h0 into hex[0],
// hex slots 1..T poisoned, ctrl init. gates are NOT precomputed (mega does).
// ---------------------------------------------------------------------------
__global__ __launch_bounds__(256) void prep_kernel(
    const float* __restrict__ enc_h, const float* __restrict__ W_ih,
    const float* __restrict__ W_hh, const float* __restrict__ b_ih,
    const float* __restrict__ b_hh, const float* __restrict__ W_out,
    const float* __restrict__ emb,
    u16* __restrict__ wih_p, u16* __restrict__ whh_p, u16* __restrict__ wout_b,
    float* __restrict__ bias_p, u16* __restrict__ emb16,
    u16* __restrict__ hex, u32* __restrict__ ctrl) {
  int idx = blockIdx.x * 256 + threadIdx.x;
  int stride = gridDim.x * 256;
  if (idx < 128) { ctrl[idx] = POISON32; ctrl[128 + idx] = POISON32; ctrl[256 + idx] = POISON32; }
  if (idx < 8) ctrl[384 + idx] = 0;
  const int N0 = NG * NE, N1 = NG * NH, N2 = NV * NH, N3 = NG, N4 = NB * NH, N5 = NV * NE;
  int total = N0 + N1 + N2 + N3 + N4 + N5;
  for (int i = idx; i < total; i += stride) {
    int j = i;
    if (j < N0) {
      int r = j >> 8, k = j & 255;
      int orig = (r & 3) * NH + (r >> 2);
      wih_p[j] = f2bf(W_ih[orig * NE + k]);
    } else if ((j -= N0) < N1) {
      int r = j >> 9, k = j & 511;
      int orig = (r & 3) * NH + (r >> 2);
      whh_p[j] = f2bf(W_hh[orig * NH + k]);
    } else if ((j -= N1) < N2) {
      wout_b[j] = f2bf(W_out[j]);
    } else if ((j -= N2) < N3) {
      int orig = (j & 3) * NH + (j >> 2);
      bias_p[j] = b_ih[orig] + b_hh[orig];
    } else if ((j -= N3) < N4) {
      int bb = j >> 9, jj = j & 511;
      float v = 0.5f * (enc_h[j] + enc_h[N4 + j]);
      hex[((size_t)(bb >> 4) * 16 + (jj >> 5)) * 512 + (size_t)(bb & 15) * 32 + (jj & 31)] = f2bf(v);
    } else {
      j -= N4;
      emb16[j] = f2bf(fmaxf(emb[j], 0.f));  // relu folded into the table
    }
  }
  u64* hp = (u64*)(hex + HEX_T);
  const int NP = NT * (HEX_T / 4);
  for (int i = idx; i < NP; i += stride) hp[i] = POISON64;
}

// ---------------------------------------------------------------------------
// Kernel 2 (MEGA, cooperative, 256 WGs x 512 thr):
//  WGs 0-127:  LSTM scan (R13-exact; gate loads sc0sc1 + rare poison re-poll).
//  WGs 128-255: workers — phase 1 produce gates (swapped-operand MFMA so each
//  lane packs 4 consecutive n into one visible 8B store); phase 2 logits +
//  fused log_softmax, writing final log-probs over the dead gates bytes.
// ---------------------------------------------------------------------------
__global__ __launch_bounds__(512, 2) void mega_kernel(
    const float* __restrict__ enc_c, const int* __restrict__ target,
    const u16* __restrict__ emb16, const u16* __restrict__ wih_p,
    const float* __restrict__ bias_p,
    const u16* __restrict__ whh_p, u16* __restrict__ hex,
    float* __restrict__ out_tail, u32* __restrict__ ctrl,
    const u16* __restrict__ wout_b, const float* __restrict__ b_out,
    u16* __restrict__ gates, float* __restrict__ out) {
  __shared__ __align__(16) u16 Hs[2][16 * 512];
  __shared__ u32 disc_lds[128];
  __shared__ int fast_sh;
  int bid = blockIdx.x, tid = threadIdx.x;
  int w = tid >> 6, lane = tid & 63, l15 = lane & 15, l4 = lane >> 4;

  if (bid < 128) {
    // ------------------------- LSTM scan (R13) -------------------------
    int g, s; bool fast;
    group_setup(ctrl, disc_lds, &fast_sh, bid, tid, g, s, fast);

    bf16x8 wreg[16];
    {
      const u16* wp = whh_p + (size_t)(s * 128 + w * 16 + l15) * NH + l4 * 8;
#pragma unroll
      for (int kk = 0; kk < 16; ++kk) {
        wreg[kk] = *(const bf16x8*)(wp + kk * 32);
        asm volatile("" : "+v"(wreg[kk]));
      }
    }
    int b = g * 16 + l15;
    int j = s * 32 + w * 4 + l4;
    float creg = 0.5f * (enc_c[b * NH + j] + enc_c[NB * NH + b * NH + j]);
    const u16* gp = gates + ((size_t)b * NT) * NG + s * 128 + w * 16 + l4 * 4;
    uint2 pg = g_load_u64(gp);
    stage_h(hex + (size_t)g * 8192, &Hs[0][0], tid, fast);
    __syncthreads();
    int cur = 0;

    for (int t = 0; t < NT; ++t) {
      asm volatile("s_waitcnt vmcnt(0)" ::: "memory");
      __builtin_amdgcn_sched_barrier(0);
      // gate poison re-poll (rare: only while workers are still ahead-racing)
      while (((pg.x & 0xFFFFu) == 0xFFFFu) | ((pg.x >> 16) == 0xFFFFu) |
             ((pg.y & 0xFFFFu) == 0xFFFFu) | ((pg.y >> 16) == 0xFFFFu)) {
        asm volatile("s_sleep 8");
        asm volatile("global_load_dwordx2 %0, %1, off sc0 sc1\n\ts_waitcnt vmcnt(0)"
                     : "=v"(pg) : "v"(gp) : "memory");
      }
      f32x4 acc;
      acc[0] = bf2f((u16)(pg.x & 0xFFFF));
      acc[1] = bf2f((u16)(pg.x >> 16));
      acc[2] = bf2f((u16)(pg.y & 0xFFFF));
      acc[3] = bf2f((u16)(pg.y >> 16));
      if (t + 1 < NT) { gp += NG; pg = g_load_u64(gp); }
#pragma unroll
      for (int kk = 0; kk < 16; ++kk) {
        bf16x8 hv = *(const bf16x8*)&Hs[cur][l15 * 512 + (((kk * 4 + l4) ^ (l15 & 7)) << 3)];
        acc = MFMA16(wreg[kk], hv, acc);
      }
      float ig = sigm(acc[0]);
      float fg = sigm(acc[1]);
      float gg = tanh_f(acc[2]);
      float og = sigm(acc[3]);
      float cn = fg * creg + ig * gg;
      creg = cn;
      float hn = og * tanh_f(cn);
      {
        u32 v = (u32)f2bf(hn);
        u32 v2 = (u32)__shfl_xor((int)v, 16, 64);
        v = v | (v2 << 16);
        u32 hi = (u32)__shfl_xor((int)v, 32, 64);
        if (l4 == 0) {
          u64 qv = (u64)v | ((u64)hi << 32);
          u16* hdst = hex + ((size_t)(t + 1) * 8 + g) * 8192;
          ex_store(hdst + ((size_t)s * 16 + l15) * 32 + w * 4, qv);
        }
      }
      if (t == NT - 1) {
        out_tail[b * NH + j] = hn;
        out_tail[NB * NH + b * NH + j] = cn;
        break;
      }
      stage_h(hex + ((size_t)(t + 1) * 8 + g) * 8192, &Hs[cur ^ 1][0], tid, fast);
      __syncthreads();
      cur ^= 1;
    }
  } else {
    // ------------------------- workers -------------------------
    int wid = bid - 128;
    // ---- Phase 1: gates for t in {wid, wid+128, wid+256, wid+384} ----
#pragma unroll 1
    for (int rep = 0; rep < 4; ++rep) {
      int t = wid + rep * 128;
#pragma unroll 1
      for (int tix = w; tix < 64; tix += 8) {
        int nBase = (tix >> 1) * 64, bBase = (tix & 1) * 64;
        int tok[4];
#pragma unroll
        for (int fn = 0; fn < 4; ++fn) {
          int bb2 = bBase + fn * 16 + l15;
          tok[fn] = (t == 0) ? 0 : target[bb2 * NT + t - 1];
        }
        f32x4 acc[4][4] = {};
#pragma unroll 1
        for (int kk = 0; kk < 8; ++kk) {
          int k0 = kk * 32 + l4 * 8;
          bf16x8 a[4], bb[4];
#pragma unroll
          for (int fm = 0; fm < 4; ++fm)
            a[fm] = *(const bf16x8*)(wih_p + (size_t)(nBase + fm * 16 + l15) * NE + k0);
#pragma unroll
          for (int fn = 0; fn < 4; ++fn)
            bb[fn] = *(const bf16x8*)(emb16 + (size_t)tok[fn] * NE + k0);
#pragma unroll
          for (int fm = 0; fm < 4; ++fm)
#pragma unroll
            for (int fn = 0; fn < 4; ++fn)
              acc[fm][fn] = MFMA16(a[fm], bb[fn], acc[fm][fn]);
        }
#pragma unroll
        for (int fm = 0; fm < 4; ++fm) {
          int n0 = nBase + fm * 16 + l4 * 4;
          float4 bv = *(const float4*)(bias_p + n0);
#pragma unroll
          for (int fn = 0; fn < 4; ++fn) {
            int bb2 = bBase + fn * 16 + l15;
            u32 lo = (u32)f2bf(acc[fm][fn][0] + bv.x) | ((u32)f2bf(acc[fm][fn][1] + bv.y) << 16);
            u32 hi = (u32)f2bf(acc[fm][fn][2] + bv.z) | ((u32)f2bf(acc[fm][fn][3] + bv.w) << 16);
            g_store_u64(gates + ((size_t)bb2 * NT + t) * NG + n0, (u64)lo | ((u64)hi << 32));
          }
        }
      }
    }
    // ---- Phase 2: logits + fused log_softmax ----
    float* redmax = (float*)&Hs[0][0];   // 512 floats
    float* redsum = redmax + 512;
#pragma unroll 1
    for (int rep = 0; rep < 4; ++rep) {
      int tt = wid + rep * 128;
      const u16* A = hex + (size_t)(tt + 1) * HEX_T;
#pragma unroll 1
      for (int mh = 0; mh < 2; ++mh) {
        f32x4 acc[2][4][4] = {};
#pragma unroll 1
        for (int kk = 0; kk < 16; ++kk) {
          bf16x8 a[4];
#pragma unroll
          for (int fm = 0; fm < 4; ++fm)
            a[fm] = w_poll_frag(A + (((size_t)(mh * 4 + fm) * 16 + kk) * 512 + l15 * 32 + l4 * 8));
          bf16x8 bb[2][4];
#pragma unroll
          for (int np = 0; np < 2; ++np)
#pragma unroll
            for (int fn = 0; fn < 4; ++fn)
              bb[np][fn] = *(const bf16x8*)(wout_b +
                  (size_t)(np * 512 + w * 64 + fn * 16 + l15) * NH + kk * 32 + l4 * 8);
#pragma unroll
          for (int np = 0; np < 2; ++np)
#pragma unroll
            for (int fm = 0; fm < 4; ++fm)
#pragma unroll
              for (int fn = 0; fn < 4; ++fn)
                acc[np][fm][fn] = MFMA16(a[fm], bb[np][fn], acc[np][fm][fn]);
        }
        // fold b_out bias
#pragma unroll
        for (int np = 0; np < 2; ++np)
#pragma unroll
          for (int fn = 0; fn < 4; ++fn) {
            float bias = b_out[np * 512 + w * 64 + fn * 16 + l15];
#pragma unroll
            for (int fm = 0; fm < 4; ++fm)
#pragma unroll
              for (int i2 = 0; i2 < 4; ++i2) acc[np][fm][fn][i2] += bias;
          }
        // row max: in-lane -> across l15 -> across waves (LDS)
        float rmax[4][4];
#pragma unroll
        for (int fm = 0; fm < 4; ++fm)
#pragma unroll
          for (int i2 = 0; i2 < 4; ++i2) {
            float pm = -1e30f;
#pragma unroll
            for (int np = 0; np < 2; ++np)
#pragma unroll
              for (int fn = 0; fn < 4; ++fn) pm = fmaxf(pm, acc[np][fm][fn][i2]);
            rmax[fm][i2] = pm;
          }
#pragma unroll
        for (int o = 1; o < 16; o <<= 1)
#pragma unroll
          for (int fm = 0; fm < 4; ++fm)
#pragma unroll
            for (int i2 = 0; i2 < 4; ++i2)
              rmax[fm][i2] = fmaxf(rmax[fm][i2], __shfl_xor(rmax[fm][i2], o, 64));
        if (l15 == 0)
#pragma unroll
          for (int fm = 0; fm < 4; ++fm)
#pragma unroll
            for (int i2 = 0; i2 < 4; ++i2)
              redmax[w * 64 + fm * 16 + l4 * 4 + i2] = rmax[fm][i2];
        __syncthreads();
#pragma unroll
        for (int fm = 0; fm < 4; ++fm)
#pragma unroll
          for (int i2 = 0; i2 < 4; ++i2) {
            float m2 = -1e30f;
#pragma unroll
            for (int w2 = 0; w2 < 8; ++w2)
              m2 = fmaxf(m2, redmax[w2 * 64 + fm * 16 + l4 * 4 + i2]);
            rmax[fm][i2] = m2;
          }
        // exp-sum
        float rsum[4][4];
#pragma unroll
        for (int fm = 0; fm < 4; ++fm)
#pragma unroll
          for (int i2 = 0; i2 < 4; ++i2) {
            float ps = 0.f;
#pragma unroll
            for (int np = 0; np < 2; ++np)
#pragma unroll
              for (int fn = 0; fn < 4; ++fn)
                ps += __expf(acc[np][fm][fn][i2] - rmax[fm][i2]);
            rsum[fm][i2] = ps;
          }
#pragma unroll
        for (int o = 1; o < 16; o <<= 1)
#pragma unroll
          for (int fm = 0; fm < 4; ++fm)
#pragma unroll
            for (int i2 = 0; i2 < 4; ++i2)
              rsum[fm][i2] += __shfl_xor(rsum[fm][i2], o, 64);
        if (l15 == 0)
#pragma unroll
          for (int fm = 0; fm < 4; ++fm)
#pragma unroll
            for (int i2 = 0; i2 < 4; ++i2)
              redsum[w * 64 + fm * 16 + l4 * 4 + i2] = rsum[fm][i2];
        __syncthreads();
#pragma unroll
        for (int fm = 0; fm < 4; ++fm)
#pragma unroll
          for (int i2 = 0; i2 < 4; ++i2) {
            float s2 = 0.f;
#pragma unroll
            for (int w2 = 0; w2 < 8; ++w2)
              s2 += redsum[w2 * 64 + fm * 16 + l4 * 4 + i2];
            rsum[fm][i2] = rmax[fm][i2] + __logf(s2);  // lse
          }
        // write log-probs
#pragma unroll
        for (int np = 0; np < 2; ++np)
#pragma unroll
          for (int fn = 0; fn < 4; ++fn) {
            int v = np * 512 + w * 64 + fn * 16 + l15;
#pragma unroll
            for (int fm = 0; fm < 4; ++fm)
#pragma unroll
              for (int i2 = 0; i2 < 4; ++i2) {
                int m = mh * 64 + fm * 16 + l4 * 4 + i2;
                out[((size_t)m * NT + tt) * NV + v] = acc[np][fm][fn][i2] - rsum[fm][i2];
              }
          }
        __syncthreads();  // protect red buffers before next block
      }
    }
  }
}

extern "C" void kernel_launch(void* const* d_in, const int* in_sizes, int n_in,
                              void* d_out, int out_size, void* d_ws, size_t ws_size,
                              hipStream_t stream) {
  (void)in_sizes; (void)n_in; (void)out_size; (void)ws_size;
  const float* enc_h  = (const float*)d_in[1];
  const float* enc_c  = (const float*)d_in[2];
  const int*   target = (const int*)d_in[3];
  const float* emb    = (const float*)d_in[4];
  const float* W_ih   = (const float*)d_in[5];
  const float* W_hh   = (const float*)d_in[6];
  const float* b_ih   = (const float*)d_in[7];
  const float* b_hh   = (const float*)d_in[8];
  const float* W_out  = (const float*)d_in[9];
  const float* b_out  = (const float*)d_in[10];

  char* ws = (char*)d_ws;
  u16*   wih_p  = (u16*)(ws);                        // 2048x256 bf16 (1 MB)
  u16*   whh_p  = (u16*)(ws + (1 << 20));            // 2048x512 bf16 (2 MB)
  u16*   wout_b = (u16*)(ws + (3 << 20));            // 1024x512 bf16 (1 MB)
  float* bias_p = (float*)(ws + (4 << 20));          // 2048 f32 (8 KB)
  u16*   emb16  = (u16*)(ws + (4 << 20) + 8192);     // relu'd 1024x256 bf16 (512 KB)
  u32*   ctrl   = (u32*)(ws + (4 << 20) + 8192 + 524288);  // discovery/probe
  u16*   hex    = (u16*)(ws + (4 << 20) + 8192 + 524288 + 8192);  // (T+1)x65536 bf16

  u16*   gates  = (u16*)d_out;                       // bf16 (b,t,n), aliases out
  float* out    = (float*)d_out;
  float* out_tail = out + (size_t)NB * NT * NV;      // h_T then c_T

  prep_kernel<<<dim3(2048), 256, 0, stream>>>(enc_h, W_ih, W_hh, b_ih, b_hh, W_out,
                                              emb, wih_p, whh_p, wout_b, bias_p,
                                              emb16, hex, ctrl);
  {
    const float* enc_c_a = enc_c;
    const int* target_a = target;
    const u16* emb16_a = emb16;
    const u16* wih_a = wih_p;
    const float* biasp_a = bias_p;
    const u16* whh_a = whh_p;
    u16* hex_a = hex;
    float* tail_a = out_tail;
    u32* ctrl_a = ctrl;
    const u16* woutb_a = wout_b;
    const float* bout_a = b_out;
    u16* gates_a = gates;
    float* out_a = out;
    void* args[] = {&enc_c_a, &target_a, &emb16_a, &wih_a, &biasp_a, &whh_a,
                    &hex_a, &tail_a, &ctrl_a, &woutb_a, &bout_a, &gates_a, &out_a};
    hipLaunchCooperativeKernel((const void*)mega_kernel, dim3(256), dim3(512),
                               args, 0, stream);
  }
}

// Round 17
// 3592.275 us; speedup vs baseline: 1.1314x; 1.0148x over previous
//
#include <hip/hip_runtime.h>

typedef unsigned short u16;
typedef unsigned int u32;
typedef unsigned long long u64;
typedef short bf16x8 __attribute__((ext_vector_type(8)));
typedef float f32x4 __attribute__((ext_vector_type(4)));
typedef unsigned u32x4 __attribute__((ext_vector_type(4)));

#define NB 128
#define NT 512
#define NV 1024
#define NE 256
#define NH 512
#define NG 2048

#define POISON64 0xFFFFFFFFFFFFFFFFULL
#define POISON32 0xFFFFFFFFu
#define HEX_T 65536  // elements per t-slot: 8 groups x 16 slots x 16 b x 32 j
#define PROBE_CYCLES 480000ULL  // ~0.2 ms @ 2.4 GHz

__device__ __forceinline__ u16 f2bf(float f) {
  union { float f; unsigned u; } v; v.f = f;
  unsigned r = v.u + 0x7FFFu + ((v.u >> 16) & 1u);
  return (u16)(r >> 16);
}
__device__ __forceinline__ float bf2f(u16 u) {
  union { unsigned u; float f; } v; v.u = ((unsigned)u) << 16;
  return v.f;
}
__device__ __forceinline__ float sigm(float x) { return 1.f / (1.f + __expf(-x)); }
__device__ __forceinline__ float tanh_f(float x) {
  x = fminf(fmaxf(x, -20.f), 20.f);
  float e = __expf(2.f * x);
  return (e - 1.f) / (e + 1.f);
}
__device__ __forceinline__ u64 memtime() {
  u64 t;
  asm volatile("s_memtime %0\n\ts_waitcnt lgkmcnt(0)" : "=s"(t));
  return t;
}

#define MFMA16(a, b, c) __builtin_amdgcn_mfma_f32_16x16x32_bf16((a), (b), (c), 0, 0, 0)

__device__ __forceinline__ u64 dc_load_u64(const void* p) {
  return __hip_atomic_load((const u64*)p, __ATOMIC_RELAXED, __HIP_MEMORY_SCOPE_AGENT);
}
// gate-stream load: sc0 sc1 (L3-coherent, cross-XCD worker->scan), no waitcnt
__device__ __forceinline__ uint2 g_load_u64(const void* p) {
  uint2 r;
  asm volatile("global_load_dwordx2 %0, %1, off sc0 sc1" : "=v"(r) : "v"(p) : "memory");
  return r;
}
// exchange store: ATOMIC exchange (R13-proven; executes at coherence point)
__device__ __forceinline__ void ex_store(u16* p, u64 v) {
  (void)__hip_atomic_exchange((u64*)p, v, __ATOMIC_RELAXED, __HIP_MEMORY_SCOPE_AGENT);
}
// visible 8B store for worker-produced gates (R8-proven globally visible)
__device__ __forceinline__ void g_store_u64(u16* p, u64 v) {
  asm volatile("global_store_dwordx2 %0, %1, off sc0 sc1" :: "v"(p), "v"(v) : "memory");
}
// exchange/poll load of 32B. fast: sc0 only -> L2-served. slow: sc0 sc1 -> L3.
__device__ __forceinline__ void ex_load2(const u16* p, bool fast, u32x4& q0, u32x4& q1) {
  if (fast) {
    asm volatile(
        "global_load_dwordx4 %0, %2, off sc0\n\t"
        "global_load_dwordx4 %1, %3, off sc0\n\t"
        "s_waitcnt vmcnt(0)"
        : "=&v"(q0), "=&v"(q1)
        : "v"(p), "v"(p + 8)
        : "memory");
  } else {
    asm volatile(
        "global_load_dwordx4 %0, %2, off sc0 sc1\n\t"
        "global_load_dwordx4 %1, %3, off sc0 sc1\n\t"
        "s_waitcnt vmcnt(0)"
        : "=&v"(q0), "=&v"(q1)
        : "v"(p), "v"(p + 8)
        : "memory");
  }
}

// lstm poll+stage one group-slice of h[t] (16KB) into LDS (R13-exact).
__device__ __forceinline__ void stage_h(const u16* hexg, u16* HsBuf, int tid, bool fast) {
  const u16* p = hexg + (size_t)tid * 16;
  u32x4 q0, q1;
  ex_load2(p, fast, q0, q1);
  for (;;) {
    u64 a = (u64)q0.x | ((u64)q0.y << 32), b = (u64)q0.z | ((u64)q0.w << 32);
    u64 c = (u64)q1.x | ((u64)q1.y << 32), d = (u64)q1.z | ((u64)q1.w << 32);
    if (!((a == POISON64) | (b == POISON64) | (c == POISON64) | (d == POISON64))) break;
    ex_load2(p, fast, q0, q1);
  }
  int s2 = tid >> 5, b = (tid >> 1) & 15, half = tid & 1;
  int K0 = s2 * 4 + half * 2;
  *(u32x4*)&HsBuf[b * 512 + ((K0 ^ (b & 7)) << 3)] = q0;
  *(u32x4*)&HsBuf[b * 512 + (((K0 + 1) ^ (b & 7)) << 3)] = q1;
}

// worker: poll one 16B A-frag (2 producer granules) via agent loads + sleep.
__device__ __forceinline__ bf16x8 w_poll_frag(const u16* p) {
  u64 lo = dc_load_u64(p), hi = dc_load_u64(p + 4);
  while (lo == POISON64 || hi == POISON64) {
    asm volatile("s_sleep 64");
    lo = dc_load_u64(p); hi = dc_load_u64(p + 4);
  }
  u32x4 q = {(u32)lo, (u32)(lo >> 32), (u32)hi, (u32)(hi >> 32)};
  return __builtin_bit_cast(bf16x8, q);
}

// discovery + probe (R13-exact): returns (g, s, fast) for lstm WGs.
__device__ __forceinline__ void group_setup(u32* ctrl, u32* disc_lds, int* fast_shp,
                                            int bid, int tid, int& g, int& s, bool& fast) {
  u32* disc = ctrl; u32* probe = ctrl + 128; u32* ready2 = ctrl + 256; u32* demote = ctrl + 384;
  int w = tid >> 6, lane = tid & 63;
  if (tid == 0) {
    u32 xcd;
    asm volatile("s_getreg_b32 %0, hwreg(HW_REG_XCC_ID)" : "=s"(xcd));
    __hip_atomic_store(&disc[bid], xcd & 7u, __ATOMIC_RELAXED, __HIP_MEMORY_SCOPE_AGENT);
  }
  if (w == 0) {
    const u64* d64 = (const u64*)disc;
    u64 v;
    do { v = __hip_atomic_load(&d64[lane], __ATOMIC_RELAXED, __HIP_MEMORY_SCOPE_AGENT); }
    while ((u32)v == POISON32 || (u32)(v >> 32) == POISON32);
    disc_lds[2 * lane] = (u32)v; disc_lds[2 * lane + 1] = (u32)(v >> 32);
  }
  __syncthreads();
  u64 cnt64 = 0;
  for (int i = 0; i < 128; ++i) cnt64 += 1ULL << ((disc_lds[i] & 7) * 8);
  int myx = (int)(disc_lds[bid] & 7);
  int rank = 0;
  for (int i = 0; i < bid; ++i) if ((int)(disc_lds[i] & 7) == myx) rank++;
  int pre = 0;
  for (int x = 0; x < myx; ++x) pre += (int)((cnt64 >> (x * 8)) & 255);
  int pos = pre + rank;
  g = pos >> 4; s = pos & 15;
  fast = false;
  { int p0 = 0;
    for (int x = 0; x < 8; ++x) { int c = (int)((cnt64 >> (x * 8)) & 255);
      if (p0 <= g * 16 && g * 16 + 16 <= p0 + c) fast = true; p0 += c; } }
  if (fast) {
    if (tid == 0)
      (void)__hip_atomic_exchange(&probe[g * 16 + s], 1u, __ATOMIC_RELAXED,
                                  __HIP_MEMORY_SCOPE_AGENT);
    if (w == 0) {
      bool to = false;
      if (lane < 16) {
        u32 pv = POISON32;
        u64 t0 = memtime();
        for (;;) {
          asm volatile("global_load_dword %0, %1, off sc0\n\ts_waitcnt vmcnt(0)"
                       : "=v"(pv) : "v"(&probe[g * 16 + lane]) : "memory");
          if (pv != POISON32) break;
          if (memtime() - t0 > PROBE_CYCLES) break;
        }
        to = (pv == POISON32);
      }
      if (__any(to) && lane == 0) {
        __hip_atomic_store(&demote[g], 1u, __ATOMIC_RELAXED, __HIP_MEMORY_SCOPE_AGENT);
        asm volatile("s_waitcnt vmcnt(0)" ::: "memory");
      }
    }
    __syncthreads();
    if (tid == 0)
      __hip_atomic_store(&ready2[g * 16 + s], 1u, __ATOMIC_RELAXED, __HIP_MEMORY_SCOPE_AGENT);
    if (w == 0 && lane < 16) {
      u32 rv;
      do { rv = __hip_atomic_load(&ready2[g * 16 + lane], __ATOMIC_RELAXED, __HIP_MEMORY_SCOPE_AGENT); }
      while (rv == POISON32);
    }
    if (tid == 0)
      *fast_shp = (int)(__hip_atomic_load(&demote[g], __ATOMIC_RELAXED, __HIP_MEMORY_SCOPE_AGENT) == 0u);
    __syncthreads();
    fast = (*fast_shp != 0);
  }
}

// ---------------------------------------------------------------------------
// Kernel 1: weight prep, relu'd bf16 embedding table, h0 into hex[0],
// hex slots 1..T poisoned, ctrl init. gates are NOT precomputed (mega does).
// ---------------------------------------------------------------------------
__global__ __launch_bounds__(256) void prep_kernel(
    const float* __restrict__ enc_h, const float* __restrict__ W_ih,
    const float* __restrict__ W_hh, const float* __restrict__ b_ih,
    const float* __restrict__ b_hh, const float* __restrict__ W_out,
    const float* __restrict__ emb,
    u16* __restrict__ wih_p, u16* __restrict__ whh_p, u16* __restrict__ wout_b,
    float* __restrict__ bias_p, u16* __restrict__ emb16,
    u16* __restrict__ hex, u32* __restrict__ ctrl) {
  int idx = blockIdx.x * 256 + threadIdx.x;
  int stride = gridDim.x * 256;
  if (idx < 128) { ctrl[idx] = POISON32; ctrl[128 + idx] = POISON32; ctrl[256 + idx] = POISON32; }
  if (idx < 8) ctrl[384 + idx] = 0;
  const int N0 = NG * NE, N1 = NG * NH, N2 = NV * NH, N3 = NG, N4 = NB * NH, N5 = NV * NE;
  int total = N0 + N1 + N2 + N3 + N4 + N5;
  for (int i = idx; i < total; i += stride) {
    int j = i;
    if (j < N0) {
      int r = j >> 8, k = j & 255;
      int orig = (r & 3) * NH + (r >> 2);
      wih_p[j] = f2bf(W_ih[orig * NE + k]);
    } else if ((j -= N0) < N1) {
      int r = j >> 9, k = j & 511;
      int orig = (r & 3) * NH + (r >> 2);
      whh_p[j] = f2bf(W_hh[orig * NH + k]);
    } else if ((j -= N1) < N2) {
      wout_b[j] = f2bf(W_out[j]);
    } else if ((j -= N2) < N3) {
      int orig = (j & 3) * NH + (j >> 2);
      bias_p[j] = b_ih[orig] + b_hh[orig];
    } else if ((j -= N3) < N4) {
      int bb = j >> 9, jj = j & 511;
      float v = 0.5f * (enc_h[j] + enc_h[N4 + j]);
      hex[((size_t)(bb >> 4) * 16 + (jj >> 5)) * 512 + (size_t)(bb & 15) * 32 + (jj & 31)] = f2bf(v);
    } else {
      j -= N4;
      emb16[j] = f2bf(fmaxf(emb[j], 0.f));  // relu folded into the table
    }
  }
  u64* hp = (u64*)(hex + HEX_T);
  const int NP = NT * (HEX_T / 4);
  for (int i = idx; i < NP; i += stride) hp[i] = POISON64;
}

// ---------------------------------------------------------------------------
// Kernel 2 (MEGA, cooperative, 256 WGs x 512 thr):
//  WGs 0-127:  LSTM scan (R13-exact; gate loads sc0sc1 + rare poison re-poll).
//  WGs 128-255: workers — phase 1 produce gates (rep 0 full speed for t<128;
//  reps 1-3 PACED with s_sleep chains so the 256MB write stream spreads over
//  ~1.1ms instead of a 200us burst, staying 2x ahead of scan consumption);
//  phase 2 logits + fused log_softmax over the dead gates bytes.
// ---------------------------------------------------------------------------
__global__ __launch_bounds__(512, 2) void mega_kernel(
    const float* __restrict__ enc_c, const int* __restrict__ target,
    const u16* __restrict__ emb16, const u16* __restrict__ wih_p,
    const float* __restrict__ bias_p,
    const u16* __restrict__ whh_p, u16* __restrict__ hex,
    float* __restrict__ out_tail, u32* __restrict__ ctrl,
    const u16* __restrict__ wout_b, const float* __restrict__ b_out,
    u16* __restrict__ gates, float* __restrict__ out) {
  __shared__ __align__(16) u16 Hs[2][16 * 512];
  __shared__ u32 disc_lds[128];
  __shared__ int fast_sh;
  int bid = blockIdx.x, tid = threadIdx.x;
  int w = tid >> 6, lane = tid & 63, l15 = lane & 15, l4 = lane >> 4;

  if (bid < 128) {
    // ------------------------- LSTM scan (R13) -------------------------
    int g, s; bool fast;
    group_setup(ctrl, disc_lds, &fast_sh, bid, tid, g, s, fast);

    bf16x8 wreg[16];
    {
      const u16* wp = whh_p + (size_t)(s * 128 + w * 16 + l15) * NH + l4 * 8;
#pragma unroll
      for (int kk = 0; kk < 16; ++kk) {
        wreg[kk] = *(const bf16x8*)(wp + kk * 32);
        asm volatile("" : "+v"(wreg[kk]));
      }
    }
    int b = g * 16 + l15;
    int j = s * 32 + w * 4 + l4;
    float creg = 0.5f * (enc_c[b * NH + j] + enc_c[NB * NH + b * NH + j]);
    const u16* gp = gates + ((size_t)b * NT) * NG + s * 128 + w * 16 + l4 * 4;
    uint2 pg = g_load_u64(gp);
    stage_h(hex + (size_t)g * 8192, &Hs[0][0], tid, fast);
    __syncthreads();
    int cur = 0;

    for (int t = 0; t < NT; ++t) {
      asm volatile("s_waitcnt vmcnt(0)" ::: "memory");
      __builtin_amdgcn_sched_barrier(0);
      // gate poison re-poll (rare: only while workers are still ahead-racing)
      while (((pg.x & 0xFFFFu) == 0xFFFFu) | ((pg.x >> 16) == 0xFFFFu) |
             ((pg.y & 0xFFFFu) == 0xFFFFu) | ((pg.y >> 16) == 0xFFFFu)) {
        asm volatile("s_sleep 8");
        asm volatile("global_load_dwordx2 %0, %1, off sc0 sc1\n\ts_waitcnt vmcnt(0)"
                     : "=v"(pg) : "v"(gp) : "memory");
      }
      f32x4 acc;
      acc[0] = bf2f((u16)(pg.x & 0xFFFF));
      acc[1] = bf2f((u16)(pg.x >> 16));
      acc[2] = bf2f((u16)(pg.y & 0xFFFF));
      acc[3] = bf2f((u16)(pg.y >> 16));
      if (t + 1 < NT) { gp += NG; pg = g_load_u64(gp); }
#pragma unroll
      for (int kk = 0; kk < 16; ++kk) {
        bf16x8 hv = *(const bf16x8*)&Hs[cur][l15 * 512 + (((kk * 4 + l4) ^ (l15 & 7)) << 3)];
        acc = MFMA16(wreg[kk], hv, acc);
      }
      float ig = sigm(acc[0]);
      float fg = sigm(acc[1]);
      float gg = tanh_f(acc[2]);
      float og = sigm(acc[3]);
      float cn = fg * creg + ig * gg;
      creg = cn;
      float hn = og * tanh_f(cn);
      {
        u32 v = (u32)f2bf(hn);
        u32 v2 = (u32)__shfl_xor((int)v, 16, 64);
        v = v | (v2 << 16);
        u32 hi = (u32)__shfl_xor((int)v, 32, 64);
        if (l4 == 0) {
          u64 qv = (u64)v | ((u64)hi << 32);
          u16* hdst = hex + ((size_t)(t + 1) * 8 + g) * 8192;
          ex_store(hdst + ((size_t)s * 16 + l15) * 32 + w * 4, qv);
        }
      }
      if (t == NT - 1) {
        out_tail[b * NH + j] = hn;
        out_tail[NB * NH + b * NH + j] = cn;
        break;
      }
      stage_h(hex + ((size_t)(t + 1) * 8 + g) * 8192, &Hs[cur ^ 1][0], tid, fast);
      __syncthreads();
      cur ^= 1;
    }
  } else {
    // ------------------------- workers -------------------------
    int wid = bid - 128;
    // ---- Phase 1: gates for t in {wid, wid+128, wid+256, wid+384} ----
#pragma unroll 1
    for (int rep = 0; rep < 4; ++rep) {
      int t = wid + rep * 128;
#pragma unroll 1
      for (int tix = w; tix < 64; tix += 8) {
        int nBase = (tix >> 1) * 64, bBase = (tix & 1) * 64;
        int tok[4];
#pragma unroll
        for (int fn = 0; fn < 4; ++fn) {
          int bb2 = bBase + fn * 16 + l15;
          tok[fn] = (t == 0) ? 0 : target[bb2 * NT + t - 1];
        }
        f32x4 acc[4][4] = {};
#pragma unroll 1
        for (int kk = 0; kk < 8; ++kk) {
          int k0 = kk * 32 + l4 * 8;
          bf16x8 a[4], bb[4];
#pragma unroll
          for (int fm = 0; fm < 4; ++fm)
            a[fm] = *(const bf16x8*)(wih_p + (size_t)(nBase + fm * 16 + l15) * NE + k0);
#pragma unroll
          for (int fn = 0; fn < 4; ++fn)
            bb[fn] = *(const bf16x8*)(emb16 + (size_t)tok[fn] * NE + k0);
#pragma unroll
          for (int fm = 0; fm < 4; ++fm)
#pragma unroll
            for (int fn = 0; fn < 4; ++fn)
              acc[fm][fn] = MFMA16(a[fm], bb[fn], acc[fm][fn]);
        }
#pragma unroll
        for (int fm = 0; fm < 4; ++fm) {
          int n0 = nBase + fm * 16 + l4 * 4;
          float4 bv = *(const float4*)(bias_p + n0);
#pragma unroll
          for (int fn = 0; fn < 4; ++fn) {
            int bb2 = bBase + fn * 16 + l15;
            u32 lo = (u32)f2bf(acc[fm][fn][0] + bv.x) | ((u32)f2bf(acc[fm][fn][1] + bv.y) << 16);
            u32 hi = (u32)f2bf(acc[fm][fn][2] + bv.z) | ((u32)f2bf(acc[fm][fn][3] + bv.w) << 16);
            g_store_u64(gates + ((size_t)bb2 * NT + t) * NG + n0, (u64)lo | ((u64)hi << 32));
          }
        }
        // pace reps 1-3: spread the write stream (scan only needs t=128+rep*128
        // after ~0.8+rep*0.8 ms; this keeps production ~2x ahead, burst-free)
        if (rep > 0) {
#pragma unroll 1
          for (int z = 0; z < rep * 12; ++z) asm volatile("s_sleep 64");
        }
      }
    }
    // ---- Phase 2: logits + fused log_softmax ----
    float* redmax = (float*)&Hs[0][0];   // 512 floats
    float* redsum = redmax + 512;
#pragma unroll 1
    for (int rep = 0; rep < 4; ++rep) {
      int tt = wid + rep * 128;
      const u16* A = hex + (size_t)(tt + 1) * HEX_T;
#pragma unroll 1
      for (int mh = 0; mh < 2; ++mh) {
        f32x4 acc[2][4][4] = {};
#pragma unroll 1
        for (int kk = 0; kk < 16; ++kk) {
          bf16x8 a[4];
#pragma unroll
          for (int fm = 0; fm < 4; ++fm)
            a[fm] = w_poll_frag(A + (((size_t)(mh * 4 + fm) * 16 + kk) * 512 + l15 * 32 + l4 * 8));
          bf16x8 bb[2][4];
#pragma unroll
          for (int np = 0; np < 2; ++np)
#pragma unroll
            for (int fn = 0; fn < 4; ++fn)
              bb[np][fn] = *(const bf16x8*)(wout_b +
                  (size_t)(np * 512 + w * 64 + fn * 16 + l15) * NH + kk * 32 + l4 * 8);
#pragma unroll
          for (int np = 0; np < 2; ++np)
#pragma unroll
            for (int fm = 0; fm < 4; ++fm)
#pragma unroll
              for (int fn = 0; fn < 4; ++fn)
                acc[np][fm][fn] = MFMA16(a[fm], bb[np][fn], acc[np][fm][fn]);
        }
        // fold b_out bias
#pragma unroll
        for (int np = 0; np < 2; ++np)
#pragma unroll
          for (int fn = 0; fn < 4; ++fn) {
            float bias = b_out[np * 512 + w * 64 + fn * 16 + l15];
#pragma unroll
            for (int fm = 0; fm < 4; ++fm)
#pragma unroll
              for (int i2 = 0; i2 < 4; ++i2) acc[np][fm][fn][i2] += bias;
          }
        // row max: in-lane -> across l15 -> across waves (LDS)
        float rmax[4][4];
#pragma unroll
        for (int fm = 0; fm < 4; ++fm)
#pragma unroll
          for (int i2 = 0; i2 < 4; ++i2) {
            float pm = -1e30f;
#pragma unroll
            for (int np = 0; np < 2; ++np)
#pragma unroll
              for (int fn = 0; fn < 4; ++fn) pm = fmaxf(pm, acc[np][fm][fn][i2]);
            rmax[fm][i2] = pm;
          }
#pragma unroll
        for (int o = 1; o < 16; o <<= 1)
#pragma unroll
          for (int fm = 0; fm < 4; ++fm)
#pragma unroll
            for (int i2 = 0; i2 < 4; ++i2)
              rmax[fm][i2] = fmaxf(rmax[fm][i2], __shfl_xor(rmax[fm][i2], o, 64));
        if (l15 == 0)
#pragma unroll
          for (int fm = 0; fm < 4; ++fm)
#pragma unroll
            for (int i2 = 0; i2 < 4; ++i2)
              redmax[w * 64 + fm * 16 + l4 * 4 + i2] = rmax[fm][i2];
        __syncthreads();
#pragma unroll
        for (int fm = 0; fm < 4; ++fm)
#pragma unroll
          for (int i2 = 0; i2 < 4; ++i2) {
            float m2 = -1e30f;
#pragma unroll
            for (int w2 = 0; w2 < 8; ++w2)
              m2 = fmaxf(m2, redmax[w2 * 64 + fm * 16 + l4 * 4 + i2]);
            rmax[fm][i2] = m2;
          }
        // exp-sum
        float rsum[4][4];
#pragma unroll
        for (int fm = 0; fm < 4; ++fm)
#pragma unroll
          for (int i2 = 0; i2 < 4; ++i2) {
            float ps = 0.f;
#pragma unroll
            for (int np = 0; np < 2; ++np)
#pragma unroll
              for (int fn = 0; fn < 4; ++fn)
                ps += __expf(acc[np][fm][fn][i2] - rmax[fm][i2]);
            rsum[fm][i2] = ps;
          }
#pragma unroll
        for (int o = 1; o < 16; o <<= 1)
#pragma unroll
          for (int fm = 0; fm < 4; ++fm)
#pragma unroll
            for (int i2 = 0; i2 < 4; ++i2)
              rsum[fm][i2] += __shfl_xor(rsum[fm][i2], o, 64);
        if (l15 == 0)
#pragma unroll
          for (int fm = 0; fm < 4; ++fm)
#pragma unroll
            for (int i2 = 0; i2 < 4; ++i2)
              redsum[w * 64 + fm * 16 + l4 * 4 + i2] = rsum[fm][i2];
        __syncthreads();
#pragma unroll
        for (int fm = 0; fm < 4; ++fm)
#pragma unroll
          for (int i2 = 0; i2 < 4; ++i2) {
            float s2 = 0.f;
#pragma unroll
            for (int w2 = 0; w2 < 8; ++w2)
              s2 += redsum[w2 * 64 + fm * 16 + l4 * 4 + i2];
            rsum[fm][i2] = rmax[fm][i2] + __logf(s2);  // lse
          }
        // write log-probs
#pragma unroll
        for (int np = 0; np < 2; ++np)
#pragma unroll
          for (int fn = 0; fn < 4; ++fn) {
            int v = np * 512 + w * 64 + fn * 16 + l15;
#pragma unroll
            for (int fm = 0; fm < 4; ++fm)
#pragma unroll
              for (int i2 = 0; i2 < 4; ++i2) {
                int m = mh * 64 + fm * 16 + l4 * 4 + i2;
                out[((size_t)m * NT + tt) * NV + v] = acc[np][fm][fn][i2] - rsum[fm][i2];
              }
          }
        __syncthreads();  // protect red buffers before next block
      }
    }
  }
}

extern "C" void kernel_launch(void* const* d_in, const int* in_sizes, int n_in,
                              void* d_out, int out_size, void* d_ws, size_t ws_size,
                              hipStream_t stream) {
  (void)in_sizes; (void)n_in; (void)out_size; (void)ws_size;
  const float* enc_h  = (const float*)d_in[1];
  const float* enc_c  = (const float*)d_in[2];
  const int*   target = (const int*)d_in[3];
  const float* emb    = (const float*)d_in[4];
  const float* W_ih   = (const float*)d_in[5];
  const float* W_hh   = (const float*)d_in[6];
  const float* b_ih   = (const float*)d_in[7];
  const float* b_hh   = (const float*)d_in[8];
  const float* W_out  = (const float*)d_in[9];
  const float* b_out  = (const float*)d_in[10];

  char* ws = (char*)d_ws;
  u16*   wih_p  = (u16*)(ws);                        // 2048x256 bf16 (1 MB)
  u16*   whh_p  = (u16*)(ws + (1 << 20));            // 2048x512 bf16 (2 MB)
  u16*   wout_b = (u16*)(ws + (3 << 20));            // 1024x512 bf16 (1 MB)
  float* bias_p = (float*)(ws + (4 << 20));          // 2048 f32 (8 KB)
  u16*   emb16  = (u16*)(ws + (4 << 20) + 8192);     // relu'd 1024x256 bf16 (512 KB)
  u32*   ctrl   = (u32*)(ws + (4 << 20) + 8192 + 524288);  // discovery/probe
  u16*   hex    = (u16*)(ws + (4 << 20) + 8192 + 524288 + 8192);  // (T+1)x65536 bf16

  u16*   gates  = (u16*)d_out;                       // bf16 (b,t,n), aliases out
  float* out    = (float*)d_out;
  float* out_tail = out + (size_t)NB * NT * NV;      // h_T then c_T

  prep_kernel<<<dim3(2048), 256, 0, stream>>>(enc_h, W_ih, W_hh, b_ih, b_hh, W_out,
                                              emb, wih_p, whh_p, wout_b, bias_p,
                                              emb16, hex, ctrl);
  {
    const float* enc_c_a = enc_c;
    const int* target_a = target;
    const u16* emb16_a = emb16;
    const u16* wih_a = wih_p;
    const float* biasp_a = bias_p;
    const u16* whh_a = whh_p;
    u16* hex_a = hex;
    float* tail_a = out_tail;
    u32* ctrl_a = ctrl;
    const u16* woutb_a = wout_b;
    const float* bout_a = b_out;
    u16* gates_a = gates;
    float* out_a = out;
    void* args[] = {&enc_c_a, &target_a, &emb16_a, &wih_a, &biasp_a, &whh_a,
                    &hex_a, &tail_a, &ctrl_a, &woutb_a, &bout_a, &gates_a, &out_a};
    hipLaunchCooperativeKernel((const void*)mega_kernel, dim3(256), dim3(512),
                               args, 0, stream);
  }
}